// Round 3
// baseline (2029.833 us; speedup 1.0000x reference)
//
#include <hip/hip_runtime.h>

typedef unsigned short u16;
typedef unsigned int u32;
typedef short bf16x8 __attribute__((ext_vector_type(8)));
typedef float f32x4 __attribute__((ext_vector_type(4)));

#define S_LEN 500
#define NB 256
#define EDIM 128

__device__ __forceinline__ float bf2f(u16 u) { return __uint_as_float(((u32)u) << 16); }
__device__ __forceinline__ u16 f2bf(float f) {
    u32 x = __float_as_uint(f);
    x += 0x7FFFu + ((x >> 16) & 1u);   // round-to-nearest-even
    return (u16)(x >> 16);
}
__device__ __forceinline__ float fexp(float x) { return __builtin_amdgcn_exp2f(x * 1.44269504089f); }
__device__ __forceinline__ float frcp(float x) { return __builtin_amdgcn_rcpf(x); }
__device__ __forceinline__ float sigm(float x) { return frcp(1.0f + fexp(-x)); }
__device__ __forceinline__ float tanh_(float x) { return 1.0f - 2.0f * frcp(1.0f + fexp(2.0f * x)); }
__device__ __forceinline__ int iclamp(int v, int hi) { return v < 0 ? 0 : (v > hi ? hi : v); }

// ---------------------------------------------------------------------------
// Raw workgroup barrier WITHOUT vmcnt drain. __syncthreads() lowers with a
// conservative s_waitcnt vmcnt(0) drain of the global prefetch queue. Here:
// explicit lgkmcnt(0) (my LDS writes complete -> visible CU-wide) followed by
// the COMPILER-AWARE builtin s_barrier (convergence-safe, no implicit
// waitcnt). This is the m201/HipKittens-verified pattern; round 2's opaque
// asm "s_barrier" variant is convergence-invisible and was a hang suspect.
// ---------------------------------------------------------------------------
__device__ __forceinline__ void wgbar() {
    __asm__ volatile("s_waitcnt lgkmcnt(0)" ::: "memory");
    __builtin_amdgcn_s_barrier();
}

// ---------------------------------------------------------------------------
// Runtime float-dtype detection from q_embedding bit patterns (wave-uniform).
// ---------------------------------------------------------------------------
__device__ __forceinline__ bool detect_bf16(const void* q) {
    const u16* w = (const u16*)q;
    int plaus = 0;
#pragma unroll 1
    for (int i = 0; i < 64; ++i) {
        const u16 v = w[2 * i];
        const int e = (v >> 7) & 0xFF;
        plaus += (v == 0 || (e >= 100 && e <= 130)) ? 1 : 0;
    }
    return plaus >= 48;
}
__device__ __forceinline__ float ldF(const void* p, int i, bool bf) {
    return bf ? bf2f(((const u16*)p)[i]) : ((const float*)p)[i];
}
template <bool BF>
__device__ __forceinline__ bf16x8 ldfragT(const void* p, int i) {
    if (BF) return *(const bf16x8*)((const u16*)p + i);
    const float* f = (const float*)p + i;
    bf16x8 r;
#pragma unroll
    for (int e = 0; e < 8; ++e) r[e] = (short)f2bf(f[e]);
    return r;
}

__global__ void dimkt_sentinel(u16* __restrict__ out, u16 val) {
    out[blockIdx.x * 256 + threadIdx.x] = val;
}

// ---------------------------------------------------------------------------
// K0: tiny gather-table precompute (always-fp32 outputs, packed for the scan).
// ---------------------------------------------------------------------------
__global__ void dimkt_tabs(const void* __restrict__ q_emb,
                           const void* __restrict__ c_tab, const void* __restrict__ sd_tab,
                           const void* __restrict__ qd_tab, const void* __restrict__ a_tab,
                           const void* __restrict__ W1, const void* __restrict__ W4,
                           const void* __restrict__ W5, const void* __restrict__ W6,
                           const void* __restrict__ b4, const void* __restrict__ b5,
                           const void* __restrict__ b6,
                           float* __restrict__ cW1p, float* __restrict__ sdQ,
                           float* __restrict__ qdQ, float* __restrict__ aW6p,
                           float* __restrict__ c4t, float* __restrict__ c5t) {
    const bool bf = detect_bf16(q_emb);
    __shared__ float src[128];
    const int r = blockIdx.x, n = threadIdx.x;
    const int w = n >> 5, jj = (n >> 4) & 1, l = n & 15;
    const void* srcp; const void* W; const void* bias = nullptr;
    int soff, koff, ld, oidx; float* outp; bool mask;
    if (r < 1001)      { srcp = c_tab;  soff = r * 128;               W = W1; koff = 128; ld = 512; outp = cW1p; oidx = r * 128 + w * 32 + l * 2 + jj;        mask = (r == 0); }
    else if (r < 1103) { int rr = r - 1001; srcp = sd_tab; soff = rr * 128; W = W1; koff = 256; ld = 512; outp = sdQ;  oidx = rr * 256 + w * 64 + l * 4 + jj;     mask = (rr == 0); }
    else if (r < 1205) { int rr = r - 1103; srcp = qd_tab; soff = rr * 128; W = W1; koff = 384; ld = 512; outp = qdQ;  oidx = rr * 256 + w * 64 + l * 4 + jj;     mask = (rr == 0); }
    else if (r < 1307) { int rr = r - 1205; srcp = sd_tab; soff = rr * 128; W = W6; koff = 256; ld = 512; outp = sdQ;  oidx = rr * 256 + w * 64 + l * 4 + 2 + jj; mask = (rr == 0); }
    else if (r < 1409) { int rr = r - 1307; srcp = qd_tab; soff = rr * 128; W = W6; koff = 384; ld = 512; outp = qdQ;  oidx = rr * 256 + w * 64 + l * 4 + 2 + jj; mask = (rr == 0); }
    else if (r < 1411) { int rr = r - 1409; srcp = a_tab;  soff = rr * 128; W = W6; koff = 128; ld = 512; outp = aW6p; oidx = rr * 128 + w * 32 + l * 2 + jj;     bias = b6; mask = false; }
    else if (r < 1413) { int rr = r - 1411; srcp = a_tab;  soff = rr * 128; W = W4; koff = 128; ld = 256; outp = c4t;  oidx = rr * 128 + n;                       bias = b4; mask = false; }
    else               { int rr = r - 1413; srcp = a_tab;  soff = rr * 128; W = W5; koff = 128; ld = 256; outp = c5t;  oidx = rr * 128 + n;                       bias = b5; mask = false; }
    src[n] = ldF(srcp, soff + n, bf);
    __syncthreads();
    float acc = 0.f;
    if (!mask) {
        for (int k = 0; k < 128; ++k) acc += src[k] * ldF(W, n * ld + koff + k, bf);
        if (bias) acc += ldF(bias, n, bf);
    }
    outp[oidx] = acc;
}

// ---------------------------------------------------------------------------
// K2: fused 500-step scan. 16 WGs x 256 threads. Wave wv owns cols
// [32wv,32wv+32). Weights register-resident. sd/qd/a gather tables are
// LDS-resident (staged once in prologue). The two in-loop phase syncs are
// lgkmcnt(0) + builtin s_barrier (NO vmcnt drain -> global prefetch in flight).
// ---------------------------------------------------------------------------
template <bool BF>
__global__ __launch_bounds__(256, 1) void dimkt_scan(
    const void* __restrict__ q_emb,
    const int* __restrict__ cI, const int* __restrict__ sI,
    const int* __restrict__ qI, const int* __restrict__ aI,
    const void* __restrict__ W1, const void* __restrict__ b1,
    const void* __restrict__ W2, const void* __restrict__ b2,
    const void* __restrict__ W3, const void* __restrict__ b3,
    const void* __restrict__ W4, const void* __restrict__ W5,
    const void* __restrict__ W6, const void* __restrict__ knowledge,
    const float* __restrict__ cW1p, const float* __restrict__ sdQ,
    const float* __restrict__ qdQ, const float* __restrict__ aW6p,
    const float* __restrict__ c4t, const float* __restrict__ c5t,
    void* __restrict__ outv) {
    if (detect_bf16(q_emb) != BF) return;   // wrong specialization: uniform exit
    // 136-ushort row stride: 272B = 17*16B -> 16B-aligned ds_read_b128
    __shared__ __align__(16) u16 kbuf[16][136];
    __shared__ __align__(16) u16 qqbuf[16][136];
    __shared__ __align__(16) u16 sdbuf[16][136];
    // dynamic LDS: resident gather tables
    extern __shared__ __align__(16) u16 dynLDS[];
    u16* sdT = dynLDS;                       // [102][256] bf16 (52,224 B)
    u16* qdT = dynLDS + 26112;               // [102][256] bf16 (52,224 B)
    float* aW6L = (float*)(dynLDS + 52224);  // [2][128]  f32  ( 1,024 B)

    const int tid = threadIdx.x;
    const int wv = tid >> 6, lane = tid & 63;
    const int quad = lane >> 4, l15 = lane & 15;
    const int b0 = blockIdx.x * 16;

    // ---- stationary weight fragments (registers, 500-step resident) ----
    bf16x8 fW1[2][4], fW2[2][4], fW3[2][4], fW4[2][4], fW5[2][4], fW6[2][4];
    float b1v[2], b2v[2], b3v[2], c4_0[2], c4_1[2], c5_0[2], c5_1[2];
    int col_[2];
#pragma unroll
    for (int j = 0; j < 2; ++j) {
        const int col = wv * 32 + j * 16 + l15;
        col_[j] = col;
#pragma unroll
        for (int ks = 0; ks < 4; ++ks) {
            const int ko = ks * 32 + quad * 8;
            fW1[j][ks] = ldfragT<BF>(W1, col * 512 + ko);   // W1[:, :128]
            fW2[j][ks] = ldfragT<BF>(W2, col * 128 + ko);
            fW3[j][ks] = ldfragT<BF>(W3, col * 128 + ko);
            fW4[j][ks] = ldfragT<BF>(W4, col * 256 + ko);   // W4[:, :128]
            fW5[j][ks] = ldfragT<BF>(W5, col * 256 + ko);   // W5[:, :128]
            fW6[j][ks] = ldfragT<BF>(W6, col * 512 + ko);   // W6[:, :128]
        }
        b1v[j] = ldF(b1, col, BF);
        b2v[j] = ldF(b2, col, BF);
        b3v[j] = ldF(b3, col, BF);
        c4_0[j] = c4t[col]; c4_1[j] = c4t[128 + col];
        c5_0[j] = c5t[col]; c5_1[j] = c5t[128 + col];
    }

    // ---- t=0 init: gathers (global, one-time), inp_0 via MFMA, kbuf/qqbuf, z6c
    float kold[2][4], z6c[2][4], g[2][4];
    int ac[4];
    {
        float inpAdd0[2][4];
#pragma unroll
        for (int i = 0; i < 4; ++i) {
            const int off = (b0 + quad * 4 + i) * S_LEN + 0;
            const int cx = iclamp(cI[off], 1000);
            const int sx = iclamp(sI[off], 101);
            const int qx = iclamp(qI[off], 101);
            const int ax = iclamp(aI[off], 1);
            ac[i] = ax;
            const float2 cg = *(const float2*)(cW1p + cx * 128 + wv * 32 + l15 * 2);
            const float4 sg = *(const float4*)(sdQ + sx * 256 + wv * 64 + l15 * 4);
            const float4 qg = *(const float4*)(qdQ + qx * 256 + wv * 64 + l15 * 4);
            const float2 ag = *(const float2*)(aW6p + ax * 128 + wv * 32 + l15 * 2);
            inpAdd0[0][i] = cg.x + sg.x + qg.x + b1v[0];
            inpAdd0[1][i] = cg.y + sg.y + qg.y + b1v[1];
            z6c[0][i] = ag.x + sg.z + qg.z;
            z6c[1][i] = ag.y + sg.w + qg.w;
        }
        bf16x8 ae0[4];
#pragma unroll
        for (int ks = 0; ks < 4; ++ks)
            ae0[ks] = ldfragT<BF>(q_emb, ((b0 + l15) * S_LEN + 0) * EDIM + ks * 32 + quad * 8);
        f32x4 Y1[2];
#pragma unroll
        for (int j = 0; j < 2; ++j) {
            Y1[j] = (f32x4){inpAdd0[j][0], inpAdd0[j][1], inpAdd0[j][2], inpAdd0[j][3]};
#pragma unroll
            for (int ks = 0; ks < 4; ++ks)
                Y1[j] = __builtin_amdgcn_mfma_f32_16x16x32_bf16(ae0[ks], fW1[j][ks], Y1[j], 0, 0, 0);
        }
#pragma unroll
        for (int j = 0; j < 2; ++j) {
            const float k0 = ldF(knowledge, col_[j], BF);
#pragma unroll
            for (int i = 0; i < 4; ++i) {
                kold[j][i] = k0;
                const int row = quad * 4 + i;
                kbuf[row][col_[j]] = f2bf(k0);
                qqbuf[row][col_[j]] = f2bf(k0 - Y1[j][i]);
            }
        }
    }
    // ---- prime pipeline: q_emb[1] fragments + raw idx[1] ----
    bf16x8 aeNow[4], aeFut[4];
#pragma unroll
    for (int ks = 0; ks < 4; ++ks)
        aeNow[ks] = ldfragT<BF>(q_emb, ((b0 + l15) * S_LEN + 1) * EDIM + ks * 32 + quad * 8);
    int cN[4], sN[4], qN[4], aN[4], cF[4], sF[4], qF[4], aF[4];
#pragma unroll
    for (int i = 0; i < 4; ++i) {
        const int off = (b0 + quad * 4 + i) * S_LEN + 1;
        cN[i] = cI[off]; sN[i] = sI[off]; qN[i] = qI[off]; aN[i] = aI[off];
    }

    // ---- stage resident gather tables into LDS (sd/qd bf16, aW6 f32) ----
#pragma unroll 1
    for (int v = tid; v < 6528; v += 256) {          // 6528 float4s = 102*256 f32
        const float4 a4 = *(const float4*)(sdQ + v * 4);
        const float4 b4_ = *(const float4*)(qdQ + v * 4);
        ushort4 sa, sb;
        sa.x = f2bf(a4.x);  sa.y = f2bf(a4.y);  sa.z = f2bf(a4.z);  sa.w = f2bf(a4.w);
        sb.x = f2bf(b4_.x); sb.y = f2bf(b4_.y); sb.z = f2bf(b4_.z); sb.w = f2bf(b4_.w);
        *(ushort4*)(sdT + v * 4) = sa;
        *(ushort4*)(qdT + v * 4) = sb;
    }
    aW6L[tid] = aW6p[tid];                           // 256 floats, 256 threads

    __syncthreads();   // one real barrier pre-loop (drains weight+table loads once)

#pragma unroll 1
    for (int t = 0; t < S_LEN; ++t) {
        // ---- issue prefetch: q_emb/idx for t+2 (raw, consumed next iter) ----
        const int tf = (t + 2 < S_LEN) ? t + 2 : S_LEN - 1;
#pragma unroll
        for (int ks = 0; ks < 4; ++ks)
            aeFut[ks] = ldfragT<BF>(q_emb, ((b0 + l15) * S_LEN + tf) * EDIM + ks * 32 + quad * 8);
#pragma unroll
        for (int i = 0; i < 4; ++i) {
            const int off = (b0 + quad * 4 + i) * S_LEN + tf;
            cF[i] = cI[off]; sF[i] = sI[off]; qF[i] = qI[off]; aF[i] = aI[off];
        }
        // ---- c-table gather for t+1 (only remaining in-loop global gather);
        //      sd/qd/a indices clamped now, read from LDS in phase C ----
        float2 cg[4];
        int an[4], sxv[4], qxv[4];
#pragma unroll
        for (int i = 0; i < 4; ++i) {
            const int cx = iclamp(cN[i], 1000);
            sxv[i] = iclamp(sN[i], 101);
            qxv[i] = iclamp(qN[i], 101);
            an[i]  = iclamp(aN[i], 1);
            cg[i] = *(const float2*)(cW1p + cx * 128 + wv * 32 + l15 * 2);
        }

        // ---- phase B: Y2/Y3 on qq, Y6 on k, Y1n on ae(t+1); sdft -> LDS ----
        bf16x8 aq[4], ak[4];
#pragma unroll
        for (int ks = 0; ks < 4; ++ks) {
            aq[ks] = *(const bf16x8*)&qqbuf[l15][ks * 32 + quad * 8];
            ak[ks] = *(const bf16x8*)&kbuf[l15][ks * 32 + quad * 8];
        }
        f32x4 Y2[2], Y3[2], Y6[2], Y1n[2];
#pragma unroll
        for (int j = 0; j < 2; ++j) {
            Y2[j] = (f32x4){b2v[j], b2v[j], b2v[j], b2v[j]};
            Y3[j] = (f32x4){b3v[j], b3v[j], b3v[j], b3v[j]};
            Y6[j] = (f32x4){z6c[j][0], z6c[j][1], z6c[j][2], z6c[j][3]};
            Y1n[j] = (f32x4){b1v[j], b1v[j], b1v[j], b1v[j]};
#pragma unroll
            for (int ks = 0; ks < 4; ++ks) {
                Y2[j] = __builtin_amdgcn_mfma_f32_16x16x32_bf16(aq[ks], fW2[j][ks], Y2[j], 0, 0, 0);
                Y3[j] = __builtin_amdgcn_mfma_f32_16x16x32_bf16(aq[ks], fW3[j][ks], Y3[j], 0, 0, 0);
                Y6[j] = __builtin_amdgcn_mfma_f32_16x16x32_bf16(ak[ks], fW6[j][ks], Y6[j], 0, 0, 0);
                Y1n[j] = __builtin_amdgcn_mfma_f32_16x16x32_bf16(aeNow[ks], fW1[j][ks], Y1n[j], 0, 0, 0);
            }
        }
#pragma unroll
        for (int j = 0; j < 2; ++j)
#pragma unroll
            for (int i = 0; i < 4; ++i) {
                const float sdv = sigm(Y2[j][i]) * tanh_(Y3[j][i]);
                sdbuf[quad * 4 + i][col_[j]] = f2bf(sdv);
                g[j][i] = sigm(Y6[j][i]);
            }
        wgbar();

        // ---- phase C: sd/qd/a from resident LDS tables; Y4/Y5 on sdft;
        //      k update; write k/qq for t+1 ----
        ushort4 sv4[4], qv4[4]; float2 agv[4];
#pragma unroll
        for (int i = 0; i < 4; ++i) {
            sv4[i] = *(const ushort4*)(sdT + sxv[i] * 256 + wv * 64 + l15 * 4);
            qv4[i] = *(const ushort4*)(qdT + qxv[i] * 256 + wv * 64 + l15 * 4);
            agv[i] = *(const float2*)(aW6L + an[i] * 128 + wv * 32 + l15 * 2);
        }
        bf16x8 as[4];
#pragma unroll
        for (int ks = 0; ks < 4; ++ks)
            as[ks] = *(const bf16x8*)&sdbuf[l15][ks * 32 + quad * 8];
        f32x4 Y4[2], Y5[2];
#pragma unroll
        for (int j = 0; j < 2; ++j) {
            Y4[j] = (f32x4){ac[0] ? c4_1[j] : c4_0[j], ac[1] ? c4_1[j] : c4_0[j],
                            ac[2] ? c4_1[j] : c4_0[j], ac[3] ? c4_1[j] : c4_0[j]};
            Y5[j] = (f32x4){ac[0] ? c5_1[j] : c5_0[j], ac[1] ? c5_1[j] : c5_0[j],
                            ac[2] ? c5_1[j] : c5_0[j], ac[3] ? c5_1[j] : c5_0[j]};
#pragma unroll
            for (int ks = 0; ks < 4; ++ks) {
                Y4[j] = __builtin_amdgcn_mfma_f32_16x16x32_bf16(as[ks], fW4[j][ks], Y4[j], 0, 0, 0);
                Y5[j] = __builtin_amdgcn_mfma_f32_16x16x32_bf16(as[ks], fW5[j][ks], Y5[j], 0, 0, 0);
            }
        }
#pragma unroll
        for (int j = 0; j < 2; ++j)
#pragma unroll
            for (int i = 0; i < 4; ++i) {
                const float pk = sigm(Y4[j][i]) * tanh_(Y5[j][i]);
                const float kn = g[j][i] * kold[j][i] + (1.0f - g[j][i]) * pk;
                kold[j][i] = kn;
                const float inpn = Y1n[j][i] +
                    ((j == 0) ? (cg[i].x + bf2f(sv4[i].x) + bf2f(qv4[i].x))
                              : (cg[i].y + bf2f(sv4[i].y) + bf2f(qv4[i].y)));
                const int row = quad * 4 + i;
                kbuf[row][col_[j]] = f2bf(kn);
                qqbuf[row][col_[j]] = f2bf(kn - inpn);   // qq_{t+1}
            }
        // ---- rotate pipeline registers; z6 for t+1 ----
#pragma unroll
        for (int i = 0; i < 4; ++i) {
            z6c[0][i] = agv[i].x + bf2f(sv4[i].z) + bf2f(qv4[i].z);
            z6c[1][i] = agv[i].y + bf2f(sv4[i].w) + bf2f(qv4[i].w);
            ac[i] = an[i];
            cN[i] = cF[i]; sN[i] = sF[i]; qN[i] = qF[i]; aN[i] = aF[i];
        }
#pragma unroll
        for (int ks = 0; ks < 4; ++ks) aeNow[ks] = aeFut[ks];
        wgbar();
    }

    // ---- epilogue: out = sigmoid(k_final), [B][E], dtype matches input ----
#pragma unroll
    for (int j = 0; j < 2; ++j)
#pragma unroll
        for (int i = 0; i < 4; ++i) {
            const int row = quad * 4 + i;
            const float v = sigm(kold[j][i]);
            const int off = (b0 + row) * EDIM + col_[j];
            if (BF) ((u16*)outv)[off] = f2bf(v);
            else    ((float*)outv)[off] = v;
        }
}

// ---------------------------------------------------------------------------
extern "C" void kernel_launch(void* const* d_in, const int* in_sizes, int n_in,
                              void* d_out, int out_size, void* d_ws, size_t ws_size,
                              hipStream_t stream) {
    static const int exp_sizes[27] = {
        128000, 128000, 128000, 128000, 128000,
        128000, 128000, 128000, 128000,
        16384000,
        128128, 13056, 13056, 256, 128,
        65536, 128, 16384, 128, 16384, 128,
        32768, 128, 32768, 128, 65536, 128
    };
    bool sizes_ok = (n_in == 27) && (out_size == 32768);
    if (sizes_ok)
        for (int i = 0; i < 27; ++i)
            if (in_sizes[i] != exp_sizes[i]) { sizes_ok = false; break; }
    if (!sizes_ok) {
        dimkt_sentinel<<<dim3(128), dim3(256), 0, stream>>>((u16*)d_out, (u16)0xC080); // -4.0
        return;
    }
    const size_t WS_NEED = 724480;
    if (ws_size < WS_NEED) {
        dimkt_sentinel<<<dim3(128), dim3(256), 0, stream>>>((u16*)d_out, (u16)0x4110); // 9.0
        return;
    }

    const int* c   = (const int*)d_in[1];
    const int* sd  = (const int*)d_in[2];
    const int* qd  = (const int*)d_in[3];
    const int* a   = (const int*)d_in[4];
    const void* q_emb = d_in[9];
    const void* c_tab = d_in[10];
    const void* sd_tab = d_in[11];
    const void* qd_tab = d_in[12];
    const void* a_tab = d_in[13];
    const void* knowledge = d_in[14];
    const void* W1 = d_in[15]; const void* b1 = d_in[16];
    const void* W2 = d_in[17]; const void* b2 = d_in[18];
    const void* W3 = d_in[19]; const void* b3 = d_in[20];
    const void* W4 = d_in[21]; const void* b4 = d_in[22];
    const void* W5 = d_in[23]; const void* b5 = d_in[24];
    const void* W6 = d_in[25]; const void* b6 = d_in[26];

    float* wsf = (float*)d_ws;
    float* cW1p = wsf;                 // 1001*128
    float* sdQ  = wsf + 128128;        // 102*256
    float* qdQ  = wsf + 154240;        // 102*256
    float* aW6p = wsf + 180352;        // 2*128 (+b6)
    float* c4t  = wsf + 180608;        // 2*128 (+b4)
    float* c5t  = wsf + 180864;        // 2*128 (+b5), ends at 181120 floats

    // dynamic LDS for resident gather tables: 2*(102*256*2B) + 2*128*4B
    constexpr int DYN_BYTES = 26112 * 2 * 2 + 1024;   // 105,472 B
    hipFuncSetAttribute(reinterpret_cast<const void*>(&dimkt_scan<true>),
                        hipFuncAttributeMaxDynamicSharedMemorySize, DYN_BYTES);
    hipFuncSetAttribute(reinterpret_cast<const void*>(&dimkt_scan<false>),
                        hipFuncAttributeMaxDynamicSharedMemorySize, DYN_BYTES);

    dimkt_tabs<<<dim3(1415), dim3(128), 0, stream>>>(
        q_emb, c_tab, sd_tab, qd_tab, a_tab, W1, W4, W5, W6, b4, b5, b6,
        cW1p, sdQ, qdQ, aW6p, c4t, c5t);

    dimkt_scan<true><<<dim3(16), dim3(256), DYN_BYTES, stream>>>(
        q_emb, c, sd, qd, a, W1, b1, W2, b2, W3, b3, W4, W5, W6, knowledge,
        cW1p, sdQ, qdQ, aW6p, c4t, c5t, d_out);
    dimkt_scan<false><<<dim3(16), dim3(256), DYN_BYTES, stream>>>(
        q_emb, c, sd, qd, a, W1, b1, W2, b2, W3, b3, W4, W5, W6, knowledge,
        cW1p, sdQ, qdQ, aW6p, c4t, c5t, d_out);
}

// Round 4
// 1340.319 us; speedup vs baseline: 1.5144x; 1.5144x over previous
//
#include <hip/hip_runtime.h>

typedef unsigned short u16;
typedef unsigned int u32;
typedef short bf16x8 __attribute__((ext_vector_type(8)));
typedef float f32x4 __attribute__((ext_vector_type(4)));

#define S_LEN 500
#define NB 256
#define EDIM 128

__device__ __forceinline__ float bf2f(u16 u) { return __uint_as_float(((u32)u) << 16); }
__device__ __forceinline__ u16 f2bf(float f) {
    u32 x = __float_as_uint(f);
    x += 0x7FFFu + ((x >> 16) & 1u);   // round-to-nearest-even
    return (u16)(x >> 16);
}
__device__ __forceinline__ float fexp(float x) { return __builtin_amdgcn_exp2f(x * 1.44269504089f); }
__device__ __forceinline__ float frcp(float x) { return __builtin_amdgcn_rcpf(x); }
__device__ __forceinline__ float sigm(float x) { return frcp(1.0f + fexp(-x)); }
__device__ __forceinline__ float tanh_(float x) { return 1.0f - 2.0f * frcp(1.0f + fexp(2.0f * x)); }
__device__ __forceinline__ int iclamp(int v, int hi) { return v < 0 ? 0 : (v > hi ? hi : v); }

// ---------------------------------------------------------------------------
// R1-proven workgroup sync: lane-0 atomicAdd on an LDS counter + broadcast
// poll. Measured FASTER than raw s_barrier on this kernel (1490 vs 1878 us).
// ---------------------------------------------------------------------------
__device__ __forceinline__ void wgsync(volatile int* c, int target) {
    __asm__ volatile("s_waitcnt lgkmcnt(0)" ::: "memory");  // prior LDS writes done
    if ((threadIdx.x & 63) == 0) atomicAdd((int*)c, 1);
    while (*c < target) {}
    __asm__ volatile("" ::: "memory");
}

// ---------------------------------------------------------------------------
// Runtime float-dtype detection from q_embedding bit patterns (wave-uniform).
// ---------------------------------------------------------------------------
__device__ __forceinline__ bool detect_bf16(const void* q) {
    const u16* w = (const u16*)q;
    int plaus = 0;
#pragma unroll 1
    for (int i = 0; i < 64; ++i) {
        const u16 v = w[2 * i];
        const int e = (v >> 7) & 0xFF;
        plaus += (v == 0 || (e >= 100 && e <= 130)) ? 1 : 0;
    }
    return plaus >= 48;
}
__device__ __forceinline__ float ldF(const void* p, int i, bool bf) {
    return bf ? bf2f(((const u16*)p)[i]) : ((const float*)p)[i];
}
template <bool BF>
__device__ __forceinline__ bf16x8 ldfragT(const void* p, int i) {
    if (BF) return *(const bf16x8*)((const u16*)p + i);
    const float* f = (const float*)p + i;
    bf16x8 r;
#pragma unroll
    for (int e = 0; e < 8; ++e) r[e] = (short)f2bf(f[e]);
    return r;
}

__global__ void dimkt_sentinel(u16* __restrict__ out, u16 val) {
    out[blockIdx.x * 256 + threadIdx.x] = val;
}

// ---------------------------------------------------------------------------
// K-conv: one-time q_emb f32 -> bf16 (only when input really is f32; the
// detect guard prevents any OOB read when the input is already bf16).
// ---------------------------------------------------------------------------
__global__ void dimkt_qe16(const float* __restrict__ qf, u16* __restrict__ qe16) {
    if (detect_bf16(qf)) return;                     // bf16 input: buffer unused
    const int i = (blockIdx.x * 256 + threadIdx.x) * 8;
    const float4 a = *(const float4*)(qf + i);
    const float4 b = *(const float4*)(qf + i + 4);
    ushort4 lo, hi;
    lo.x = f2bf(a.x); lo.y = f2bf(a.y); lo.z = f2bf(a.z); lo.w = f2bf(a.w);
    hi.x = f2bf(b.x); hi.y = f2bf(b.y); hi.z = f2bf(b.z); hi.w = f2bf(b.w);
    *(ushort4*)(qe16 + i) = lo;
    *(ushort4*)(qe16 + i + 4) = hi;
}

// ---------------------------------------------------------------------------
// K0: tiny gather-table precompute (always-fp32 outputs, packed for the scan).
// ---------------------------------------------------------------------------
__global__ void dimkt_tabs(const void* __restrict__ q_emb,
                           const void* __restrict__ c_tab, const void* __restrict__ sd_tab,
                           const void* __restrict__ qd_tab, const void* __restrict__ a_tab,
                           const void* __restrict__ W1, const void* __restrict__ W4,
                           const void* __restrict__ W5, const void* __restrict__ W6,
                           const void* __restrict__ b4, const void* __restrict__ b5,
                           const void* __restrict__ b6,
                           float* __restrict__ cW1p, float* __restrict__ sdQ,
                           float* __restrict__ qdQ, float* __restrict__ aW6p,
                           float* __restrict__ c4t, float* __restrict__ c5t) {
    const bool bf = detect_bf16(q_emb);
    __shared__ float src[128];
    const int r = blockIdx.x, n = threadIdx.x;
    const int w = n >> 5, jj = (n >> 4) & 1, l = n & 15;
    const void* srcp; const void* W; const void* bias = nullptr;
    int soff, koff, ld, oidx; float* outp; bool mask;
    if (r < 1001)      { srcp = c_tab;  soff = r * 128;               W = W1; koff = 128; ld = 512; outp = cW1p; oidx = r * 128 + w * 32 + l * 2 + jj;        mask = (r == 0); }
    else if (r < 1103) { int rr = r - 1001; srcp = sd_tab; soff = rr * 128; W = W1; koff = 256; ld = 512; outp = sdQ;  oidx = rr * 256 + w * 64 + l * 4 + jj;     mask = (rr == 0); }
    else if (r < 1205) { int rr = r - 1103; srcp = qd_tab; soff = rr * 128; W = W1; koff = 384; ld = 512; outp = qdQ;  oidx = rr * 256 + w * 64 + l * 4 + jj;     mask = (rr == 0); }
    else if (r < 1307) { int rr = r - 1205; srcp = sd_tab; soff = rr * 128; W = W6; koff = 256; ld = 512; outp = sdQ;  oidx = rr * 256 + w * 64 + l * 4 + 2 + jj; mask = (rr == 0); }
    else if (r < 1409) { int rr = r - 1307; srcp = qd_tab; soff = rr * 128; W = W6; koff = 384; ld = 512; outp = qdQ;  oidx = rr * 256 + w * 64 + l * 4 + 2 + jj; mask = (rr == 0); }
    else if (r < 1411) { int rr = r - 1409; srcp = a_tab;  soff = rr * 128; W = W6; koff = 128; ld = 512; outp = aW6p; oidx = rr * 128 + w * 32 + l * 2 + jj;     bias = b6; mask = false; }
    else if (r < 1413) { int rr = r - 1411; srcp = a_tab;  soff = rr * 128; W = W4; koff = 128; ld = 256; outp = c4t;  oidx = rr * 128 + n;                       bias = b4; mask = false; }
    else               { int rr = r - 1413; srcp = a_tab;  soff = rr * 128; W = W5; koff = 128; ld = 256; outp = c5t;  oidx = rr * 128 + n;                       bias = b5; mask = false; }
    src[n] = ldF(srcp, soff + n, bf);
    __syncthreads();
    float acc = 0.f;
    if (!mask) {
        for (int k = 0; k < 128; ++k) acc += src[k] * ldF(W, n * ld + koff + k, bf);
        if (bias) acc += ldF(bias, n, bf);
    }
    outp[oidx] = acc;
}

// ---------------------------------------------------------------------------
// K2: fused 500-step scan. 16 WGs x 256 threads. Wave wv owns cols
// [32wv,32wv+32). Weights register-resident. sd/qd/a gather tables
// LDS-resident. NEW: all indices packed once into LDS (c|sd|qd|a -> u32,
// [16][500] = 32 KB, 4 broadcast ds_reads/step replace 16 global loads);
// ae fragments read from pre-converted bf16 q_emb (1 vector load/frag on the
// f32 input path instead of 8 scalar loads + cvt). Sync: R1-proven LDS spin.
// ---------------------------------------------------------------------------
template <bool BF>
__global__ __launch_bounds__(256, 1) void dimkt_scan(
    const void* __restrict__ q_emb, const u16* __restrict__ qe16, const int use16,
    const int* __restrict__ cI, const int* __restrict__ sI,
    const int* __restrict__ qI, const int* __restrict__ aI,
    const void* __restrict__ W1, const void* __restrict__ b1,
    const void* __restrict__ W2, const void* __restrict__ b2,
    const void* __restrict__ W3, const void* __restrict__ b3,
    const void* __restrict__ W4, const void* __restrict__ W5,
    const void* __restrict__ W6, const void* __restrict__ knowledge,
    const float* __restrict__ cW1p, const float* __restrict__ sdQ,
    const float* __restrict__ qdQ, const float* __restrict__ aW6p,
    const float* __restrict__ c4t, const float* __restrict__ c5t,
    void* __restrict__ outv) {
    if (detect_bf16(q_emb) != BF) return;   // wrong specialization: uniform exit
    // 136-ushort row stride: 272B = 17*16B -> 16B-aligned ds_read_b128
    __shared__ __align__(16) u16 kbuf[16][136];
    __shared__ __align__(16) u16 qqbuf[16][136];
    __shared__ __align__(16) u16 sdbuf[16][136];
    __shared__ u32 idxL[16][S_LEN];          // packed c|sd|qd|a (32,000 B)
    __shared__ int sctr;
    // dynamic LDS: resident gather tables
    extern __shared__ __align__(16) u16 dynLDS[];
    u16* sdT = dynLDS;                       // [102][256] bf16 (52,224 B)
    u16* qdT = dynLDS + 26112;               // [102][256] bf16 (52,224 B)
    float* aW6L = (float*)(dynLDS + 52224);  // [2][128]  f32  ( 1,024 B)

    const int tid = threadIdx.x;
    const int wv = tid >> 6, lane = tid & 63;
    const int quad = lane >> 4, l15 = lane & 15;
    const int b0 = blockIdx.x * 16;

    // ae fragment loader: bf16 direct, or pre-converted bf16, or scalar-f32
    const bool fastAE = BF || (use16 != 0);
    const u16* aesrc = BF ? (const u16*)q_emb : qe16;
#define AEOFF(T, KS) (((b0 + l15) * S_LEN + (T)) * EDIM + (KS) * 32 + quad * 8)

    // ---- stationary weight fragments (registers, 500-step resident) ----
    bf16x8 fW1[2][4], fW2[2][4], fW3[2][4], fW4[2][4], fW5[2][4], fW6[2][4];
    float b1v[2], b2v[2], b3v[2], c4_0[2], c4_1[2], c5_0[2], c5_1[2];
    int col_[2];
#pragma unroll
    for (int j = 0; j < 2; ++j) {
        const int col = wv * 32 + j * 16 + l15;
        col_[j] = col;
#pragma unroll
        for (int ks = 0; ks < 4; ++ks) {
            const int ko = ks * 32 + quad * 8;
            fW1[j][ks] = ldfragT<BF>(W1, col * 512 + ko);   // W1[:, :128]
            fW2[j][ks] = ldfragT<BF>(W2, col * 128 + ko);
            fW3[j][ks] = ldfragT<BF>(W3, col * 128 + ko);
            fW4[j][ks] = ldfragT<BF>(W4, col * 256 + ko);   // W4[:, :128]
            fW5[j][ks] = ldfragT<BF>(W5, col * 256 + ko);   // W5[:, :128]
            fW6[j][ks] = ldfragT<BF>(W6, col * 512 + ko);   // W6[:, :128]
        }
        b1v[j] = ldF(b1, col, BF);
        b2v[j] = ldF(b2, col, BF);
        b3v[j] = ldF(b3, col, BF);
        c4_0[j] = c4t[col]; c4_1[j] = c4t[128 + col];
        c5_0[j] = c5t[col]; c5_1[j] = c5t[128 + col];
    }

    // ---- pack all per-step indices into LDS (one-time) ----
#pragma unroll 1
    for (int r = 0; r < 16; ++r)
#pragma unroll 1
        for (int t = tid; t < S_LEN; t += 256) {
            const int off = (b0 + r) * S_LEN + t;
            idxL[r][t] = (u32)iclamp(cI[off], 1000)
                       | ((u32)iclamp(sI[off], 101) << 10)
                       | ((u32)iclamp(qI[off], 101) << 17)
                       | ((u32)iclamp(aI[off], 1) << 24);
        }

    // ---- stage resident gather tables into LDS (sd/qd bf16, aW6 f32) ----
#pragma unroll 1
    for (int v = tid; v < 6528; v += 256) {          // 6528 float4s = 102*256 f32
        const float4 a4 = *(const float4*)(sdQ + v * 4);
        const float4 b4_ = *(const float4*)(qdQ + v * 4);
        ushort4 sa, sb;
        sa.x = f2bf(a4.x);  sa.y = f2bf(a4.y);  sa.z = f2bf(a4.z);  sa.w = f2bf(a4.w);
        sb.x = f2bf(b4_.x); sb.y = f2bf(b4_.y); sb.z = f2bf(b4_.z); sb.w = f2bf(b4_.w);
        *(ushort4*)(sdT + v * 4) = sa;
        *(ushort4*)(qdT + v * 4) = sb;
    }
    aW6L[tid] = aW6p[tid];                           // 256 floats, 256 threads
    if (tid == 0) sctr = 0;
    __syncthreads();                                 // idxL/tables published

    // ---- t=0 init: gathers (one-time), inp_0 via MFMA, kbuf/qqbuf, z6c ----
    float kold[2][4], z6c[2][4], g[2][4];
    int ac[4];
    {
        float inpAdd0[2][4];
#pragma unroll
        for (int i = 0; i < 4; ++i) {
            const u32 p = idxL[quad * 4 + i][0];
            const int cx = p & 1023, sx = (p >> 10) & 127;
            const int qx = (p >> 17) & 127, ax = (p >> 24) & 1;
            ac[i] = ax;
            const float2 cg = *(const float2*)(cW1p + cx * 128 + wv * 32 + l15 * 2);
            const float4 sg = *(const float4*)(sdQ + sx * 256 + wv * 64 + l15 * 4);
            const float4 qg = *(const float4*)(qdQ + qx * 256 + wv * 64 + l15 * 4);
            const float2 ag = *(const float2*)(aW6p + ax * 128 + wv * 32 + l15 * 2);
            inpAdd0[0][i] = cg.x + sg.x + qg.x + b1v[0];
            inpAdd0[1][i] = cg.y + sg.y + qg.y + b1v[1];
            z6c[0][i] = ag.x + sg.z + qg.z;
            z6c[1][i] = ag.y + sg.w + qg.w;
        }
        bf16x8 ae0[4];
#pragma unroll
        for (int ks = 0; ks < 4; ++ks)
            ae0[ks] = fastAE ? *(const bf16x8*)(aesrc + AEOFF(0, ks))
                             : ldfragT<BF>(q_emb, AEOFF(0, ks));
        f32x4 Y1[2];
#pragma unroll
        for (int j = 0; j < 2; ++j) {
            Y1[j] = (f32x4){inpAdd0[j][0], inpAdd0[j][1], inpAdd0[j][2], inpAdd0[j][3]};
#pragma unroll
            for (int ks = 0; ks < 4; ++ks)
                Y1[j] = __builtin_amdgcn_mfma_f32_16x16x32_bf16(ae0[ks], fW1[j][ks], Y1[j], 0, 0, 0);
        }
#pragma unroll
        for (int j = 0; j < 2; ++j) {
            const float k0 = ldF(knowledge, col_[j], BF);
#pragma unroll
            for (int i = 0; i < 4; ++i) {
                kold[j][i] = k0;
                const int row = quad * 4 + i;
                kbuf[row][col_[j]] = f2bf(k0);
                qqbuf[row][col_[j]] = f2bf(k0 - Y1[j][i]);
            }
        }
    }
    // ---- prime pipeline: ae(1) fragments + packed idx(1) ----
    bf16x8 aeNow[4], aeFut[4];
#pragma unroll
    for (int ks = 0; ks < 4; ++ks)
        aeNow[ks] = fastAE ? *(const bf16x8*)(aesrc + AEOFF(1, ks))
                           : ldfragT<BF>(q_emb, AEOFF(1, ks));
    u32 pk4[4];
#pragma unroll
    for (int i = 0; i < 4; ++i) pk4[i] = idxL[quad * 4 + i][1];

    __syncthreads();                                 // t0 kbuf/qqbuf published

    int bar = 0;
#pragma unroll 1
    for (int t = 0; t < S_LEN; ++t) {
        const int tf2 = (t + 2 < S_LEN) ? t + 2 : S_LEN - 1;
        // ---- unpack idx(t+1); issue cg gather (consumed late in phase C) ----
        float2 cg[4];
        int an[4], sxv[4], qxv[4];
#pragma unroll
        for (int i = 0; i < 4; ++i) {
            const u32 p = pk4[i];
            const int cx = p & 1023;
            sxv[i] = (p >> 10) & 127;
            qxv[i] = (p >> 17) & 127;
            an[i]  = (p >> 24) & 1;
            cg[i] = *(const float2*)(cW1p + cx * 128 + wv * 32 + l15 * 2);
        }
        // ---- prefetch: ae(t+2) fragments + packed idx(t+2) ----
        if (fastAE) {
#pragma unroll
            for (int ks = 0; ks < 4; ++ks)
                aeFut[ks] = *(const bf16x8*)(aesrc + AEOFF(tf2, ks));
        } else {
#pragma unroll
            for (int ks = 0; ks < 4; ++ks)
                aeFut[ks] = ldfragT<BF>(q_emb, AEOFF(tf2, ks));
        }
#pragma unroll
        for (int i = 0; i < 4; ++i) pk4[i] = idxL[quad * 4 + i][tf2];

        // ---- phase B: Y2/Y3 on qq, Y6 on k, Y1n on ae(t+1); sdft -> LDS ----
        bf16x8 aq[4], ak[4];
#pragma unroll
        for (int ks = 0; ks < 4; ++ks) {
            aq[ks] = *(const bf16x8*)&qqbuf[l15][ks * 32 + quad * 8];
            ak[ks] = *(const bf16x8*)&kbuf[l15][ks * 32 + quad * 8];
        }
        f32x4 Y2[2], Y3[2], Y6[2], Y1n[2];
#pragma unroll
        for (int j = 0; j < 2; ++j) {
            Y2[j] = (f32x4){b2v[j], b2v[j], b2v[j], b2v[j]};
            Y3[j] = (f32x4){b3v[j], b3v[j], b3v[j], b3v[j]};
            Y6[j] = (f32x4){z6c[j][0], z6c[j][1], z6c[j][2], z6c[j][3]};
            Y1n[j] = (f32x4){b1v[j], b1v[j], b1v[j], b1v[j]};
#pragma unroll
            for (int ks = 0; ks < 4; ++ks) {
                Y2[j] = __builtin_amdgcn_mfma_f32_16x16x32_bf16(aq[ks], fW2[j][ks], Y2[j], 0, 0, 0);
                Y3[j] = __builtin_amdgcn_mfma_f32_16x16x32_bf16(aq[ks], fW3[j][ks], Y3[j], 0, 0, 0);
                Y6[j] = __builtin_amdgcn_mfma_f32_16x16x32_bf16(ak[ks], fW6[j][ks], Y6[j], 0, 0, 0);
                Y1n[j] = __builtin_amdgcn_mfma_f32_16x16x32_bf16(aeNow[ks], fW1[j][ks], Y1n[j], 0, 0, 0);
            }
        }
#pragma unroll
        for (int j = 0; j < 2; ++j)
#pragma unroll
            for (int i = 0; i < 4; ++i) {
                const float sdv = sigm(Y2[j][i]) * tanh_(Y3[j][i]);
                sdbuf[quad * 4 + i][col_[j]] = f2bf(sdv);
                g[j][i] = sigm(Y6[j][i]);
            }
        bar += 4; wgsync(&sctr, bar);

        // ---- phase C: sd/qd/a from resident LDS tables; Y4/Y5 on sdft;
        //      k update; write k/qq for t+1 ----
        ushort4 sv4[4], qv4[4]; float2 agv[4];
#pragma unroll
        for (int i = 0; i < 4; ++i) {
            sv4[i] = *(const ushort4*)(sdT + sxv[i] * 256 + wv * 64 + l15 * 4);
            qv4[i] = *(const ushort4*)(qdT + qxv[i] * 256 + wv * 64 + l15 * 4);
            agv[i] = *(const float2*)(aW6L + an[i] * 128 + wv * 32 + l15 * 2);
        }
        bf16x8 as[4];
#pragma unroll
        for (int ks = 0; ks < 4; ++ks)
            as[ks] = *(const bf16x8*)&sdbuf[l15][ks * 32 + quad * 8];
        f32x4 Y4[2], Y5[2];
#pragma unroll
        for (int j = 0; j < 2; ++j) {
            Y4[j] = (f32x4){ac[0] ? c4_1[j] : c4_0[j], ac[1] ? c4_1[j] : c4_0[j],
                            ac[2] ? c4_1[j] : c4_0[j], ac[3] ? c4_1[j] : c4_0[j]};
            Y5[j] = (f32x4){ac[0] ? c5_1[j] : c5_0[j], ac[1] ? c5_1[j] : c5_0[j],
                            ac[2] ? c5_1[j] : c5_0[j], ac[3] ? c5_1[j] : c5_0[j]};
#pragma unroll
            for (int ks = 0; ks < 4; ++ks) {
                Y4[j] = __builtin_amdgcn_mfma_f32_16x16x32_bf16(as[ks], fW4[j][ks], Y4[j], 0, 0, 0);
                Y5[j] = __builtin_amdgcn_mfma_f32_16x16x32_bf16(as[ks], fW5[j][ks], Y5[j], 0, 0, 0);
            }
        }
#pragma unroll
        for (int j = 0; j < 2; ++j)
#pragma unroll
            for (int i = 0; i < 4; ++i) {
                const float pk = sigm(Y4[j][i]) * tanh_(Y5[j][i]);
                const float kn = g[j][i] * kold[j][i] + (1.0f - g[j][i]) * pk;
                kold[j][i] = kn;
                const float inpn = Y1n[j][i] +
                    ((j == 0) ? (cg[i].x + bf2f(sv4[i].x) + bf2f(qv4[i].x))
                              : (cg[i].y + bf2f(sv4[i].y) + bf2f(qv4[i].y)));
                const int row = quad * 4 + i;
                kbuf[row][col_[j]] = f2bf(kn);
                qqbuf[row][col_[j]] = f2bf(kn - inpn);   // qq_{t+1}
            }
        // ---- rotate pipeline registers; z6 for t+1 ----
#pragma unroll
        for (int i = 0; i < 4; ++i) {
            z6c[0][i] = agv[i].x + bf2f(sv4[i].z) + bf2f(qv4[i].z);
            z6c[1][i] = agv[i].y + bf2f(sv4[i].w) + bf2f(qv4[i].w);
            ac[i] = an[i];
        }
#pragma unroll
        for (int ks = 0; ks < 4; ++ks) aeNow[ks] = aeFut[ks];
        bar += 4; wgsync(&sctr, bar);
    }

    // ---- epilogue: out = sigmoid(k_final), [B][E], dtype matches input ----
#pragma unroll
    for (int j = 0; j < 2; ++j)
#pragma unroll
        for (int i = 0; i < 4; ++i) {
            const int row = quad * 4 + i;
            const float v = sigm(kold[j][i]);
            const int off = (b0 + row) * EDIM + col_[j];
            if (BF) ((u16*)outv)[off] = f2bf(v);
            else    ((float*)outv)[off] = v;
        }
#undef AEOFF
}

// ---------------------------------------------------------------------------
extern "C" void kernel_launch(void* const* d_in, const int* in_sizes, int n_in,
                              void* d_out, int out_size, void* d_ws, size_t ws_size,
                              hipStream_t stream) {
    static const int exp_sizes[27] = {
        128000, 128000, 128000, 128000, 128000,
        128000, 128000, 128000, 128000,
        16384000,
        128128, 13056, 13056, 256, 128,
        65536, 128, 16384, 128, 16384, 128,
        32768, 128, 32768, 128, 65536, 128
    };
    bool sizes_ok = (n_in == 27) && (out_size == 32768);
    if (sizes_ok)
        for (int i = 0; i < 27; ++i)
            if (in_sizes[i] != exp_sizes[i]) { sizes_ok = false; break; }
    if (!sizes_ok) {
        dimkt_sentinel<<<dim3(128), dim3(256), 0, stream>>>((u16*)d_out, (u16)0xC080); // -4.0
        return;
    }
    const size_t WS_NEED = 724480;              // hard requirement (unchanged)
    if (ws_size < WS_NEED) {
        dimkt_sentinel<<<dim3(128), dim3(256), 0, stream>>>((u16*)d_out, (u16)0x4110); // 9.0
        return;
    }
    // optional extra workspace: bf16-converted q_emb (32.77 MB)
    const size_t WS_NEED16 = WS_NEED + 32768000u;
    const int use16 = (ws_size >= WS_NEED16) ? 1 : 0;

    const int* c   = (const int*)d_in[1];
    const int* sd  = (const int*)d_in[2];
    const int* qd  = (const int*)d_in[3];
    const int* a   = (const int*)d_in[4];
    const void* q_emb = d_in[9];
    const void* c_tab = d_in[10];
    const void* sd_tab = d_in[11];
    const void* qd_tab = d_in[12];
    const void* a_tab = d_in[13];
    const void* knowledge = d_in[14];
    const void* W1 = d_in[15]; const void* b1 = d_in[16];
    const void* W2 = d_in[17]; const void* b2 = d_in[18];
    const void* W3 = d_in[19]; const void* b3 = d_in[20];
    const void* W4 = d_in[21]; const void* b4 = d_in[22];
    const void* W5 = d_in[23]; const void* b5 = d_in[24];
    const void* W6 = d_in[25]; const void* b6 = d_in[26];

    float* wsf = (float*)d_ws;
    float* cW1p = wsf;                 // 1001*128
    float* sdQ  = wsf + 128128;        // 102*256
    float* qdQ  = wsf + 154240;        // 102*256
    float* aW6p = wsf + 180352;        // 2*128 (+b6)
    float* c4t  = wsf + 180608;        // 2*128 (+b4)
    float* c5t  = wsf + 180864;        // 2*128 (+b5), ends at 181120 floats
    u16* qe16   = (u16*)((char*)d_ws + WS_NEED);   // 16,384,000 bf16

    // dynamic LDS for resident gather tables: 2*(102*256*2B) + 2*128*4B
    constexpr int DYN_BYTES = 26112 * 2 * 2 + 1024;   // 105,472 B
    hipFuncSetAttribute(reinterpret_cast<const void*>(&dimkt_scan<true>),
                        hipFuncAttributeMaxDynamicSharedMemorySize, DYN_BYTES);
    hipFuncSetAttribute(reinterpret_cast<const void*>(&dimkt_scan<false>),
                        hipFuncAttributeMaxDynamicSharedMemorySize, DYN_BYTES);

    dimkt_tabs<<<dim3(1415), dim3(128), 0, stream>>>(
        q_emb, c_tab, sd_tab, qd_tab, a_tab, W1, W4, W5, W6, b4, b5, b6,
        cW1p, sdQ, qdQ, aW6p, c4t, c5t);

    if (use16)
        dimkt_qe16<<<dim3(8000), dim3(256), 0, stream>>>((const float*)q_emb, qe16);

    dimkt_scan<true><<<dim3(16), dim3(256), DYN_BYTES, stream>>>(
        q_emb, qe16, use16, c, sd, qd, a, W1, b1, W2, b2, W3, b3, W4, W5, W6, knowledge,
        cW1p, sdQ, qdQ, aW6p, c4t, c5t, d_out);
    dimkt_scan<false><<<dim3(16), dim3(256), DYN_BYTES, stream>>>(
        q_emb, qe16, use16, c, sd, qd, a, W1, b1, W2, b2, W3, b3, W4, W5, W6, knowledge,
        cW1p, sdQ, qdQ, aW6p, c4t, c5t, d_out);
}

// Round 5
// 1270.618 us; speedup vs baseline: 1.5975x; 1.0549x over previous
//
#include <hip/hip_runtime.h>

typedef unsigned short u16;
typedef unsigned int u32;
typedef short bf16x8 __attribute__((ext_vector_type(8)));
typedef float f32x4 __attribute__((ext_vector_type(4)));

#define S_LEN 500
#define NB 256
#define EDIM 128

__device__ __forceinline__ float bf2f(u16 u) { return __uint_as_float(((u32)u) << 16); }
__device__ __forceinline__ u16 f2bf(float f) {
    u32 x = __float_as_uint(f);
    x += 0x7FFFu + ((x >> 16) & 1u);   // round-to-nearest-even
    return (u16)(x >> 16);
}
// HW packed f32->bf16 (RNE, matches f2bf): 1 inst for 2 values.
__device__ __forceinline__ u32 cvtpk(float lo, float hi) {
    u32 r;
    asm("v_cvt_pk_bf16_f32 %0, %1, %2" : "=v"(r) : "v"(lo), "v"(hi));
    return r;
}
__device__ __forceinline__ float fexp(float x) { return __builtin_amdgcn_exp2f(x * 1.44269504089f); }
__device__ __forceinline__ float frcp(float x) { return __builtin_amdgcn_rcpf(x); }
__device__ __forceinline__ float sigm(float x) { return frcp(1.0f + fexp(-x)); }
__device__ __forceinline__ float tanh_(float x) { return 1.0f - 2.0f * frcp(1.0f + fexp(2.0f * x)); }
__device__ __forceinline__ int iclamp(int v, int hi) { return v < 0 ? 0 : (v > hi ? hi : v); }

// ---------------------------------------------------------------------------
// R1-proven workgroup sync: lane-0 atomicAdd on an LDS counter + broadcast
// poll. Measured FASTER than raw s_barrier on this kernel (1490 vs 1878 us).
// ---------------------------------------------------------------------------
__device__ __forceinline__ void wgsync(volatile int* c, int target) {
    __asm__ volatile("s_waitcnt lgkmcnt(0)" ::: "memory");  // prior LDS writes done
    if ((threadIdx.x & 63) == 0) atomicAdd((int*)c, 1);
    while (*c < target) {}
    __asm__ volatile("" ::: "memory");
}

// ---------------------------------------------------------------------------
// Runtime float-dtype detection from q_embedding bit patterns (wave-uniform).
// ---------------------------------------------------------------------------
__device__ __forceinline__ bool detect_bf16(const void* q) {
    const u16* w = (const u16*)q;
    int plaus = 0;
#pragma unroll 1
    for (int i = 0; i < 64; ++i) {
        const u16 v = w[2 * i];
        const int e = (v >> 7) & 0xFF;
        plaus += (v == 0 || (e >= 100 && e <= 130)) ? 1 : 0;
    }
    return plaus >= 48;
}
__device__ __forceinline__ float ldF(const void* p, int i, bool bf) {
    return bf ? bf2f(((const u16*)p)[i]) : ((const float*)p)[i];
}
template <bool BF>
__device__ __forceinline__ bf16x8 ldfragT(const void* p, int i) {
    if (BF) return *(const bf16x8*)((const u16*)p + i);
    const float* f = (const float*)p + i;
    bf16x8 r;
#pragma unroll
    for (int e = 0; e < 8; ++e) r[e] = (short)f2bf(f[e]);
    return r;
}

__global__ void dimkt_sentinel(u16* __restrict__ out, u16 val) {
    out[blockIdx.x * 256 + threadIdx.x] = val;
}

// ---------------------------------------------------------------------------
// K-conv: one-time q_emb f32 -> bf16 (only when input really is f32).
// ---------------------------------------------------------------------------
__global__ void dimkt_qe16(const float* __restrict__ qf, u16* __restrict__ qe16) {
    if (detect_bf16(qf)) return;                     // bf16 input: buffer unused
    const int i = (blockIdx.x * 256 + threadIdx.x) * 8;
    const float4 a = *(const float4*)(qf + i);
    const float4 b = *(const float4*)(qf + i + 4);
    ushort4 lo, hi;
    lo.x = f2bf(a.x); lo.y = f2bf(a.y); lo.z = f2bf(a.z); lo.w = f2bf(a.w);
    hi.x = f2bf(b.x); hi.y = f2bf(b.y); hi.z = f2bf(b.z); hi.w = f2bf(b.w);
    *(ushort4*)(qe16 + i) = lo;
    *(ushort4*)(qe16 + i + 4) = hi;
}

// ---------------------------------------------------------------------------
// K0: tiny gather-table precompute. Layout (8-wave friendly, per-col scalar):
//   cW1p[cx*128 + col]              c-embedding @ W1
//   sdQ [sx*256 + col*2 + {0:W1,1:W6}]   (same for qdQ)
//   aW6p[ax*128 + col] (+b6)
//   c4t/c5t[ax*128 + col] (+b4/+b5)
// ---------------------------------------------------------------------------
__global__ void dimkt_tabs(const void* __restrict__ q_emb,
                           const void* __restrict__ c_tab, const void* __restrict__ sd_tab,
                           const void* __restrict__ qd_tab, const void* __restrict__ a_tab,
                           const void* __restrict__ W1, const void* __restrict__ W4,
                           const void* __restrict__ W5, const void* __restrict__ W6,
                           const void* __restrict__ b4, const void* __restrict__ b5,
                           const void* __restrict__ b6,
                           float* __restrict__ cW1p, float* __restrict__ sdQ,
                           float* __restrict__ qdQ, float* __restrict__ aW6p,
                           float* __restrict__ c4t, float* __restrict__ c5t) {
    const bool bf = detect_bf16(q_emb);
    __shared__ float src[128];
    const int r = blockIdx.x, n = threadIdx.x;
    const void* srcp; const void* W; const void* bias = nullptr;
    int soff, koff, ld, oidx; float* outp; bool mask;
    if (r < 1001)      { srcp = c_tab;  soff = r * 128;               W = W1; koff = 128; ld = 512; outp = cW1p; oidx = r * 128 + n;           mask = (r == 0); }
    else if (r < 1103) { int rr = r - 1001; srcp = sd_tab; soff = rr * 128; W = W1; koff = 256; ld = 512; outp = sdQ;  oidx = rr * 256 + n * 2;     mask = (rr == 0); }
    else if (r < 1205) { int rr = r - 1103; srcp = qd_tab; soff = rr * 128; W = W1; koff = 384; ld = 512; outp = qdQ;  oidx = rr * 256 + n * 2;     mask = (rr == 0); }
    else if (r < 1307) { int rr = r - 1205; srcp = sd_tab; soff = rr * 128; W = W6; koff = 256; ld = 512; outp = sdQ;  oidx = rr * 256 + n * 2 + 1; mask = (rr == 0); }
    else if (r < 1409) { int rr = r - 1307; srcp = qd_tab; soff = rr * 128; W = W6; koff = 384; ld = 512; outp = qdQ;  oidx = rr * 256 + n * 2 + 1; mask = (rr == 0); }
    else if (r < 1411) { int rr = r - 1409; srcp = a_tab;  soff = rr * 128; W = W6; koff = 128; ld = 512; outp = aW6p; oidx = rr * 128 + n;         bias = b6; mask = false; }
    else if (r < 1413) { int rr = r - 1411; srcp = a_tab;  soff = rr * 128; W = W4; koff = 128; ld = 256; outp = c4t;  oidx = rr * 128 + n;         bias = b4; mask = false; }
    else               { int rr = r - 1413; srcp = a_tab;  soff = rr * 128; W = W5; koff = 128; ld = 256; outp = c5t;  oidx = rr * 128 + n;         bias = b5; mask = false; }
    src[n] = ldF(srcp, soff + n, bf);
    __syncthreads();
    float acc = 0.f;
    if (!mask) {
        for (int k = 0; k < 128; ++k) acc += src[k] * ldF(W, n * ld + koff + k, bf);
        if (bias) acc += ldF(bias, n, bf);
    }
    outp[oidx] = acc;
}

// ---------------------------------------------------------------------------
// K2: fused 500-step scan. 16 WGs x 512 threads (8 waves; 2 waves/SIMD so one
// wave's dependent-chain stalls are filled by the other). Wave wv owns cols
// [16wv,16wv+16): per-thread serial VALU work HALVED vs the 4-wave version,
// and the weight-fragment register footprint halves (96 VGPRs), lifting the
// 256-VGPR cap that serialized prefetch. Tables LDS-resident; indices packed
// in LDS; bf16 ae path; cvt_pk for f32->bf16 pairs. Sync: R1-proven LDS spin.
// ---------------------------------------------------------------------------
template <bool BF>
__global__ __launch_bounds__(512, 2) void dimkt_scan(
    const void* __restrict__ q_emb, const u16* __restrict__ qe16, const int use16,
    const int* __restrict__ cI, const int* __restrict__ sI,
    const int* __restrict__ qI, const int* __restrict__ aI,
    const void* __restrict__ W1, const void* __restrict__ b1,
    const void* __restrict__ W2, const void* __restrict__ b2,
    const void* __restrict__ W3, const void* __restrict__ b3,
    const void* __restrict__ W4, const void* __restrict__ W5,
    const void* __restrict__ W6, const void* __restrict__ knowledge,
    const float* __restrict__ cW1p, const float* __restrict__ sdQ,
    const float* __restrict__ qdQ, const float* __restrict__ aW6p,
    const float* __restrict__ c4t, const float* __restrict__ c5t,
    void* __restrict__ outv) {
    if (detect_bf16(q_emb) != BF) return;   // wrong specialization: uniform exit
    // 136-ushort row stride: 272B = 17*16B -> 16B-aligned ds_read_b128
    __shared__ __align__(16) u16 kbuf[16][136];
    __shared__ __align__(16) u16 qqbuf[16][136];
    __shared__ __align__(16) u16 sdbuf[16][136];
    __shared__ u32 idxL[16][S_LEN];          // packed c|sd|qd|a (32,000 B)
    __shared__ int sctr;
    // dynamic LDS: resident gather tables (row stride 264 u16: bank-spread)
    extern __shared__ __align__(16) u16 dynLDS[];
    u16* sdT = dynLDS;                         // [102][264] bf16 pairs (53,856 B)
    u16* qdT = dynLDS + 102 * 264;             // [102][264]           (53,856 B)
    float* aW6L = (float*)(dynLDS + 2 * 102 * 264); // [2][132] f32     (1,056 B)

    const int tid = threadIdx.x;
    const int wv = tid >> 6, lane = tid & 63;
    const int quad = lane >> 4, l15 = lane & 15;
    const int b0 = blockIdx.x * 16;
    const int col = wv * 16 + l15;             // this thread's output column
    const int col2 = col * 2;

    const bool fastAE = BF || (use16 != 0);
    const u16* aesrc = BF ? (const u16*)q_emb : qe16;
#define AEOFF(T, KS) (((b0 + l15) * S_LEN + (T)) * EDIM + (KS) * 32 + quad * 8)

    // ---- stationary weight fragments (registers, 500-step resident) ----
    bf16x8 fW1[4], fW2[4], fW3[4], fW4[4], fW5[4], fW6[4];
#pragma unroll
    for (int ks = 0; ks < 4; ++ks) {
        const int ko = ks * 32 + quad * 8;
        fW1[ks] = ldfragT<BF>(W1, col * 512 + ko);   // W1[:, :128]
        fW2[ks] = ldfragT<BF>(W2, col * 128 + ko);
        fW3[ks] = ldfragT<BF>(W3, col * 128 + ko);
        fW4[ks] = ldfragT<BF>(W4, col * 256 + ko);   // W4[:, :128]
        fW5[ks] = ldfragT<BF>(W5, col * 256 + ko);   // W5[:, :128]
        fW6[ks] = ldfragT<BF>(W6, col * 512 + ko);   // W6[:, :128]
    }
    const float b1v = ldF(b1, col, BF);
    const float b2v = ldF(b2, col, BF);
    const float b3v = ldF(b3, col, BF);
    const float c4_0 = c4t[col], c4_1 = c4t[128 + col];
    const float c5_0 = c5t[col], c5_1 = c5t[128 + col];

    // ---- pack all per-step indices into LDS (one-time) ----
#pragma unroll 1
    for (int r = 0; r < 16; ++r)
#pragma unroll 1
        for (int t = tid; t < S_LEN; t += 512) {
            const int off = (b0 + r) * S_LEN + t;
            idxL[r][t] = (u32)iclamp(cI[off], 1000)
                       | ((u32)iclamp(sI[off], 101) << 10)
                       | ((u32)iclamp(qI[off], 101) << 17)
                       | ((u32)iclamp(aI[off], 1) << 24);
        }

    // ---- stage resident gather tables into LDS (sd/qd bf16, aW6 f32) ----
#pragma unroll 1
    for (int v = tid; v < 6528; v += 512) {          // 6528 float4s = 102*256 f32
        const int row = v >> 6, gx = (v & 63) * 4;
        const float4 a4 = *(const float4*)(sdQ + row * 256 + gx);
        const float4 b4_ = *(const float4*)(qdQ + row * 256 + gx);
        ushort4 sa, sb;
        sa.x = f2bf(a4.x);  sa.y = f2bf(a4.y);  sa.z = f2bf(a4.z);  sa.w = f2bf(a4.w);
        sb.x = f2bf(b4_.x); sb.y = f2bf(b4_.y); sb.z = f2bf(b4_.z); sb.w = f2bf(b4_.w);
        *(ushort4*)(sdT + row * 264 + gx) = sa;
        *(ushort4*)(qdT + row * 264 + gx) = sb;
    }
    if (tid < 256) {
        const int rr = tid >> 7, cc = tid & 127;
        aW6L[rr * 132 + cc] = aW6p[rr * 128 + cc];
    }
    if (tid == 0) sctr = 0;
    __syncthreads();                                 // idxL/tables published

    // ---- t=0 init: gathers (one-time), inp_0 via MFMA, kbuf/qqbuf, z6c ----
    float kold[4], z6c[4], g[4];
    int ac[4];
    {
        float inpAdd0[4];
#pragma unroll
        for (int i = 0; i < 4; ++i) {
            const u32 p = idxL[quad * 4 + i][0];
            const int cx = p & 1023, sx = (p >> 10) & 127;
            const int qx = (p >> 17) & 127, ax = (p >> 24) & 1;
            ac[i] = ax;
            const float cgv = cW1p[cx * 128 + col];
            const float2 sgp = *(const float2*)(sdQ + sx * 256 + col2);
            const float2 qgp = *(const float2*)(qdQ + qx * 256 + col2);
            const float agv = aW6p[ax * 128 + col];
            inpAdd0[i] = cgv + sgp.x + qgp.x + b1v;
            z6c[i] = agv + sgp.y + qgp.y;
        }
        bf16x8 ae0[4];
#pragma unroll
        for (int ks = 0; ks < 4; ++ks)
            ae0[ks] = fastAE ? *(const bf16x8*)(aesrc + AEOFF(0, ks))
                             : ldfragT<BF>(q_emb, AEOFF(0, ks));
        f32x4 Y1 = (f32x4){inpAdd0[0], inpAdd0[1], inpAdd0[2], inpAdd0[3]};
#pragma unroll
        for (int ks = 0; ks < 4; ++ks)
            Y1 = __builtin_amdgcn_mfma_f32_16x16x32_bf16(ae0[ks], fW1[ks], Y1, 0, 0, 0);
        const float k0 = ldF(knowledge, col, BF);
        const u16 k0b = f2bf(k0);
        const u32 q01 = cvtpk(k0 - Y1[0], k0 - Y1[1]);
        const u32 q23 = cvtpk(k0 - Y1[2], k0 - Y1[3]);
#pragma unroll
        for (int i = 0; i < 4; ++i) { kold[i] = k0; kbuf[quad * 4 + i][col] = k0b; }
        qqbuf[quad * 4 + 0][col] = (u16)q01;
        qqbuf[quad * 4 + 1][col] = (u16)(q01 >> 16);
        qqbuf[quad * 4 + 2][col] = (u16)q23;
        qqbuf[quad * 4 + 3][col] = (u16)(q23 >> 16);
    }
    // ---- prime pipeline: ae(1) fragments + packed idx(1) ----
    bf16x8 aeNow[4], aeFut[4];
#pragma unroll
    for (int ks = 0; ks < 4; ++ks)
        aeNow[ks] = fastAE ? *(const bf16x8*)(aesrc + AEOFF(1, ks))
                           : ldfragT<BF>(q_emb, AEOFF(1, ks));
    u32 pk4[4];
#pragma unroll
    for (int i = 0; i < 4; ++i) pk4[i] = idxL[quad * 4 + i][1];

    __syncthreads();                                 // t0 kbuf/qqbuf published

    int bar = 0;
#pragma unroll 1
    for (int t = 0; t < S_LEN; ++t) {
        const int tf2 = (t + 2 < S_LEN) ? t + 2 : S_LEN - 1;
        // ---- unpack idx(t+1); issue cg gather (consumed late in phase C) ----
        float cg[4];
        int an[4], sxv[4], qxv[4];
#pragma unroll
        for (int i = 0; i < 4; ++i) {
            const u32 p = pk4[i];
            const int cx = p & 1023;
            sxv[i] = (p >> 10) & 127;
            qxv[i] = (p >> 17) & 127;
            an[i]  = (p >> 24) & 1;
            cg[i] = cW1p[cx * 128 + col];
        }
        // ---- prefetch: ae(t+2) fragments + packed idx(t+2) ----
        if (fastAE) {
#pragma unroll
            for (int ks = 0; ks < 4; ++ks)
                aeFut[ks] = *(const bf16x8*)(aesrc + AEOFF(tf2, ks));
        } else {
#pragma unroll
            for (int ks = 0; ks < 4; ++ks)
                aeFut[ks] = ldfragT<BF>(q_emb, AEOFF(tf2, ks));
        }
#pragma unroll
        for (int i = 0; i < 4; ++i) pk4[i] = idxL[quad * 4 + i][tf2];

        // ---- phase B: Y2/Y3 on qq, Y6 on k, Y1n on ae(t+1); sdft -> LDS ----
        bf16x8 aq[4], ak[4];
#pragma unroll
        for (int ks = 0; ks < 4; ++ks) {
            aq[ks] = *(const bf16x8*)&qqbuf[l15][ks * 32 + quad * 8];
            ak[ks] = *(const bf16x8*)&kbuf[l15][ks * 32 + quad * 8];
        }
        f32x4 Y2 = (f32x4){b2v, b2v, b2v, b2v};
        f32x4 Y3 = (f32x4){b3v, b3v, b3v, b3v};
        f32x4 Y6 = (f32x4){z6c[0], z6c[1], z6c[2], z6c[3]};
        f32x4 Y1n = (f32x4){b1v, b1v, b1v, b1v};
#pragma unroll
        for (int ks = 0; ks < 4; ++ks) {
            Y2 = __builtin_amdgcn_mfma_f32_16x16x32_bf16(aq[ks], fW2[ks], Y2, 0, 0, 0);
            Y3 = __builtin_amdgcn_mfma_f32_16x16x32_bf16(aq[ks], fW3[ks], Y3, 0, 0, 0);
            Y6 = __builtin_amdgcn_mfma_f32_16x16x32_bf16(ak[ks], fW6[ks], Y6, 0, 0, 0);
            Y1n = __builtin_amdgcn_mfma_f32_16x16x32_bf16(aeNow[ks], fW1[ks], Y1n, 0, 0, 0);
        }
        float sdv[4];
#pragma unroll
        for (int i = 0; i < 4; ++i) {
            sdv[i] = sigm(Y2[i]) * tanh_(Y3[i]);
            g[i] = sigm(Y6[i]);
        }
        {
            const u32 s01 = cvtpk(sdv[0], sdv[1]), s23 = cvtpk(sdv[2], sdv[3]);
            sdbuf[quad * 4 + 0][col] = (u16)s01;
            sdbuf[quad * 4 + 1][col] = (u16)(s01 >> 16);
            sdbuf[quad * 4 + 2][col] = (u16)s23;
            sdbuf[quad * 4 + 3][col] = (u16)(s23 >> 16);
        }
        bar += 8; wgsync(&sctr, bar);

        // ---- phase C: sd/qd/a from resident LDS tables; Y4/Y5 on sdft;
        //      k update; write k/qq for t+1 ----
        float sw1[4], sw6[4], qw1[4], qw6[4], agv[4];
#pragma unroll
        for (int i = 0; i < 4; ++i) {
            const u32 sp = *(const u32*)(sdT + sxv[i] * 264 + col2);
            const u32 qp = *(const u32*)(qdT + qxv[i] * 264 + col2);
            agv[i] = aW6L[an[i] * 132 + col];
            sw1[i] = __uint_as_float(sp << 16);
            sw6[i] = __uint_as_float(sp & 0xFFFF0000u);
            qw1[i] = __uint_as_float(qp << 16);
            qw6[i] = __uint_as_float(qp & 0xFFFF0000u);
        }
        bf16x8 as[4];
#pragma unroll
        for (int ks = 0; ks < 4; ++ks)
            as[ks] = *(const bf16x8*)&sdbuf[l15][ks * 32 + quad * 8];
        f32x4 Y4 = (f32x4){ac[0] ? c4_1 : c4_0, ac[1] ? c4_1 : c4_0,
                           ac[2] ? c4_1 : c4_0, ac[3] ? c4_1 : c4_0};
        f32x4 Y5 = (f32x4){ac[0] ? c5_1 : c5_0, ac[1] ? c5_1 : c5_0,
                           ac[2] ? c5_1 : c5_0, ac[3] ? c5_1 : c5_0};
#pragma unroll
        for (int ks = 0; ks < 4; ++ks) {
            Y4 = __builtin_amdgcn_mfma_f32_16x16x32_bf16(as[ks], fW4[ks], Y4, 0, 0, 0);
            Y5 = __builtin_amdgcn_mfma_f32_16x16x32_bf16(as[ks], fW5[ks], Y5, 0, 0, 0);
        }
        float knA[4], qqA[4];
#pragma unroll
        for (int i = 0; i < 4; ++i) {
            const float pk = sigm(Y4[i]) * tanh_(Y5[i]);
            const float kn = g[i] * kold[i] + (1.0f - g[i]) * pk;
            kold[i] = kn; knA[i] = kn;
            qqA[i] = kn - (Y1n[i] + cg[i] + sw1[i] + qw1[i]);  // qq_{t+1}
        }
        {
            const u32 k01 = cvtpk(knA[0], knA[1]), k23 = cvtpk(knA[2], knA[3]);
            const u32 q01 = cvtpk(qqA[0], qqA[1]), q23 = cvtpk(qqA[2], qqA[3]);
            kbuf[quad * 4 + 0][col] = (u16)k01;
            kbuf[quad * 4 + 1][col] = (u16)(k01 >> 16);
            kbuf[quad * 4 + 2][col] = (u16)k23;
            kbuf[quad * 4 + 3][col] = (u16)(k23 >> 16);
            qqbuf[quad * 4 + 0][col] = (u16)q01;
            qqbuf[quad * 4 + 1][col] = (u16)(q01 >> 16);
            qqbuf[quad * 4 + 2][col] = (u16)q23;
            qqbuf[quad * 4 + 3][col] = (u16)(q23 >> 16);
        }
        // ---- rotate pipeline registers; z6 for t+1 ----
#pragma unroll
        for (int i = 0; i < 4; ++i) {
            z6c[i] = agv[i] + sw6[i] + qw6[i];
            ac[i] = an[i];
        }
#pragma unroll
        for (int ks = 0; ks < 4; ++ks) aeNow[ks] = aeFut[ks];
        bar += 8; wgsync(&sctr, bar);
    }

    // ---- epilogue: out = sigmoid(k_final), [B][E], dtype matches input ----
#pragma unroll
    for (int i = 0; i < 4; ++i) {
        const int row = quad * 4 + i;
        const float v = sigm(kold[i]);
        const int off = (b0 + row) * EDIM + col;
        if (BF) ((u16*)outv)[off] = f2bf(v);
        else    ((float*)outv)[off] = v;
    }
#undef AEOFF
}

// ---------------------------------------------------------------------------
extern "C" void kernel_launch(void* const* d_in, const int* in_sizes, int n_in,
                              void* d_out, int out_size, void* d_ws, size_t ws_size,
                              hipStream_t stream) {
    static const int exp_sizes[27] = {
        128000, 128000, 128000, 128000, 128000,
        128000, 128000, 128000, 128000,
        16384000,
        128128, 13056, 13056, 256, 128,
        65536, 128, 16384, 128, 16384, 128,
        32768, 128, 32768, 128, 65536, 128
    };
    bool sizes_ok = (n_in == 27) && (out_size == 32768);
    if (sizes_ok)
        for (int i = 0; i < 27; ++i)
            if (in_sizes[i] != exp_sizes[i]) { sizes_ok = false; break; }
    if (!sizes_ok) {
        dimkt_sentinel<<<dim3(128), dim3(256), 0, stream>>>((u16*)d_out, (u16)0xC080); // -4.0
        return;
    }
    const size_t WS_NEED = 724480;              // hard requirement (unchanged)
    if (ws_size < WS_NEED) {
        dimkt_sentinel<<<dim3(128), dim3(256), 0, stream>>>((u16*)d_out, (u16)0x4110); // 9.0
        return;
    }
    // optional extra workspace: bf16-converted q_emb (32.77 MB)
    const size_t WS_NEED16 = WS_NEED + 32768000u;
    const int use16 = (ws_size >= WS_NEED16) ? 1 : 0;

    const int* c   = (const int*)d_in[1];
    const int* sd  = (const int*)d_in[2];
    const int* qd  = (const int*)d_in[3];
    const int* a   = (const int*)d_in[4];
    const void* q_emb = d_in[9];
    const void* c_tab = d_in[10];
    const void* sd_tab = d_in[11];
    const void* qd_tab = d_in[12];
    const void* a_tab = d_in[13];
    const void* knowledge = d_in[14];
    const void* W1 = d_in[15]; const void* b1 = d_in[16];
    const void* W2 = d_in[17]; const void* b2 = d_in[18];
    const void* W3 = d_in[19]; const void* b3 = d_in[20];
    const void* W4 = d_in[21]; const void* b4 = d_in[22];
    const void* W5 = d_in[23]; const void* b5 = d_in[24];
    const void* W6 = d_in[25]; const void* b6 = d_in[26];

    float* wsf = (float*)d_ws;
    float* cW1p = wsf;                 // 1001*128
    float* sdQ  = wsf + 128128;        // 102*256
    float* qdQ  = wsf + 154240;        // 102*256
    float* aW6p = wsf + 180352;        // 2*128 (+b6)
    float* c4t  = wsf + 180608;        // 2*128 (+b4)
    float* c5t  = wsf + 180864;        // 2*128 (+b5), ends at 181120 floats
    u16* qe16   = (u16*)((char*)d_ws + WS_NEED);   // 16,384,000 bf16

    // dynamic LDS: 2 tables [102][264] bf16 + aW6L [2][132] f32
    constexpr int DYN_BYTES = 2 * 102 * 264 * 2 + 2 * 132 * 4;   // 108,768 B
    hipFuncSetAttribute(reinterpret_cast<const void*>(&dimkt_scan<true>),
                        hipFuncAttributeMaxDynamicSharedMemorySize, DYN_BYTES);
    hipFuncSetAttribute(reinterpret_cast<const void*>(&dimkt_scan<false>),
                        hipFuncAttributeMaxDynamicSharedMemorySize, DYN_BYTES);

    dimkt_tabs<<<dim3(1415), dim3(128), 0, stream>>>(
        q_emb, c_tab, sd_tab, qd_tab, a_tab, W1, W4, W5, W6, b4, b5, b6,
        cW1p, sdQ, qdQ, aW6p, c4t, c5t);

    if (use16)
        dimkt_qe16<<<dim3(8000), dim3(256), 0, stream>>>((const float*)q_emb, qe16);

    dimkt_scan<true><<<dim3(16), dim3(512), DYN_BYTES, stream>>>(
        q_emb, qe16, use16, c, sd, qd, a, W1, b1, W2, b2, W3, b3, W4, W5, W6, knowledge,
        cW1p, sdQ, qdQ, aW6p, c4t, c5t, d_out);
    dimkt_scan<false><<<dim3(16), dim3(512), DYN_BYTES, stream>>>(
        q_emb, qe16, use16, c, sd, qd, a, W1, b1, W2, b2, W3, b3, W4, W5, W6, knowledge,
        cW1p, sdQ, qdQ, aW6p, c4t, c5t, d_out);
}

// Round 6
// 1030.206 us; speedup vs baseline: 1.9703x; 1.2334x over previous
//
#include <hip/hip_runtime.h>

typedef unsigned short u16;
typedef unsigned int u32;
typedef short bf16x8 __attribute__((ext_vector_type(8)));
typedef float f32x4 __attribute__((ext_vector_type(4)));

#define S_LEN 500
#define NB 256
#define EDIM 128

__device__ __forceinline__ float bf2f(u16 u) { return __uint_as_float(((u32)u) << 16); }
__device__ __forceinline__ u16 f2bf(float f) {
    u32 x = __float_as_uint(f);
    x += 0x7FFFu + ((x >> 16) & 1u);   // round-to-nearest-even
    return (u16)(x >> 16);
}
// HW packed f32->bf16 (RNE, matches f2bf): 1 inst for 2 values.
__device__ __forceinline__ u32 cvtpk(float lo, float hi) {
    u32 r;
    asm("v_cvt_pk_bf16_f32 %0, %1, %2" : "=v"(r) : "v"(lo), "v"(hi));
    return r;
}
__device__ __forceinline__ float fexp(float x) { return __builtin_amdgcn_exp2f(x * 1.44269504089f); }
__device__ __forceinline__ float frcp(float x) { return __builtin_amdgcn_rcpf(x); }
__device__ __forceinline__ float sigm(float x) { return frcp(1.0f + fexp(-x)); }
__device__ __forceinline__ float tanh_(float x) { return 1.0f - 2.0f * frcp(1.0f + fexp(2.0f * x)); }
__device__ __forceinline__ int iclamp(int v, int hi) { return v < 0 ? 0 : (v > hi ? hi : v); }

// ---------------------------------------------------------------------------
// R1-proven workgroup sync: lane-0 atomicAdd on an LDS counter + broadcast
// poll. Measured FASTER than raw s_barrier on this kernel (1490 vs 1878 us).
// ---------------------------------------------------------------------------
__device__ __forceinline__ void wgsync(volatile int* c, int target) {
    __asm__ volatile("s_waitcnt lgkmcnt(0)" ::: "memory");  // prior LDS writes done
    if ((threadIdx.x & 63) == 0) atomicAdd((int*)c, 1);
    while (*c < target) {}
    __asm__ volatile("" ::: "memory");
}

// ---------------------------------------------------------------------------
// Runtime float-dtype detection from q_embedding bit patterns (wave-uniform).
// ---------------------------------------------------------------------------
__device__ __forceinline__ bool detect_bf16(const void* q) {
    const u16* w = (const u16*)q;
    int plaus = 0;
#pragma unroll 1
    for (int i = 0; i < 64; ++i) {
        const u16 v = w[2 * i];
        const int e = (v >> 7) & 0xFF;
        plaus += (v == 0 || (e >= 100 && e <= 130)) ? 1 : 0;
    }
    return plaus >= 48;
}
__device__ __forceinline__ float ldF(const void* p, int i, bool bf) {
    return bf ? bf2f(((const u16*)p)[i]) : ((const float*)p)[i];
}
template <bool BF>
__device__ __forceinline__ bf16x8 ldfragT(const void* p, int i) {
    if (BF) return *(const bf16x8*)((const u16*)p + i);
    const float* f = (const float*)p + i;
    bf16x8 r;
#pragma unroll
    for (int e = 0; e < 8; ++e) r[e] = (short)f2bf(f[e]);
    return r;
}
// runtime-dtype fragment loader (wave-uniform bf flag)
__device__ __forceinline__ bf16x8 ldfragR(const void* p, int i, bool bf) {
    if (bf) return *(const bf16x8*)((const u16*)p + i);
    const float* f = (const float*)p + i;
    bf16x8 r;
#pragma unroll
    for (int e = 0; e < 8; ++e) r[e] = (short)f2bf(f[e]);
    return r;
}

__global__ void dimkt_sentinel(u16* __restrict__ out, u16 val) {
    out[blockIdx.x * 256 + threadIdx.x] = val;
}

// ---------------------------------------------------------------------------
// K0: tiny gather-table precompute. Layout (per-col scalar):
//   cW1p[cx*128 + col]                   c-embedding @ W1
//   sdQ [sx*256 + col*2 + {0:W1,1:W6}]   (same for qdQ)
//   aW6p[ax*128 + col] (+b6) ; c4t/c5t[ax*128 + col] (+b4/+b5)
// Inner dot vectorized (float4 / ushort4x2); summation order unchanged.
// ---------------------------------------------------------------------------
__global__ void dimkt_tabs(const void* __restrict__ q_emb,
                           const void* __restrict__ c_tab, const void* __restrict__ sd_tab,
                           const void* __restrict__ qd_tab, const void* __restrict__ a_tab,
                           const void* __restrict__ W1, const void* __restrict__ W4,
                           const void* __restrict__ W5, const void* __restrict__ W6,
                           const void* __restrict__ b4, const void* __restrict__ b5,
                           const void* __restrict__ b6,
                           float* __restrict__ cW1p, float* __restrict__ sdQ,
                           float* __restrict__ qdQ, float* __restrict__ aW6p,
                           float* __restrict__ c4t, float* __restrict__ c5t) {
    const bool bf = detect_bf16(q_emb);
    __shared__ float src[128];
    const int r = blockIdx.x, n = threadIdx.x;
    const void* srcp; const void* W; const void* bias = nullptr;
    int soff, koff, ld, oidx; float* outp; bool mask;
    if (r < 1001)      { srcp = c_tab;  soff = r * 128;               W = W1; koff = 128; ld = 512; outp = cW1p; oidx = r * 128 + n;           mask = (r == 0); }
    else if (r < 1103) { int rr = r - 1001; srcp = sd_tab; soff = rr * 128; W = W1; koff = 256; ld = 512; outp = sdQ;  oidx = rr * 256 + n * 2;     mask = (rr == 0); }
    else if (r < 1205) { int rr = r - 1103; srcp = qd_tab; soff = rr * 128; W = W1; koff = 384; ld = 512; outp = qdQ;  oidx = rr * 256 + n * 2;     mask = (rr == 0); }
    else if (r < 1307) { int rr = r - 1205; srcp = sd_tab; soff = rr * 128; W = W6; koff = 256; ld = 512; outp = sdQ;  oidx = rr * 256 + n * 2 + 1; mask = (rr == 0); }
    else if (r < 1409) { int rr = r - 1307; srcp = qd_tab; soff = rr * 128; W = W6; koff = 384; ld = 512; outp = qdQ;  oidx = rr * 256 + n * 2 + 1; mask = (rr == 0); }
    else if (r < 1411) { int rr = r - 1409; srcp = a_tab;  soff = rr * 128; W = W6; koff = 128; ld = 512; outp = aW6p; oidx = rr * 128 + n;         bias = b6; mask = false; }
    else if (r < 1413) { int rr = r - 1411; srcp = a_tab;  soff = rr * 128; W = W4; koff = 128; ld = 256; outp = c4t;  oidx = rr * 128 + n;         bias = b4; mask = false; }
    else               { int rr = r - 1413; srcp = a_tab;  soff = rr * 128; W = W5; koff = 128; ld = 256; outp = c5t;  oidx = rr * 128 + n;         bias = b5; mask = false; }
    src[n] = ldF(srcp, soff + n, bf);
    __syncthreads();
    float acc = 0.f;
    if (!mask) {
        if (bf) {
            const u16* Wp = (const u16*)W + n * ld + koff;
#pragma unroll 4
            for (int k = 0; k < 128; k += 8) {
                const ushort4 wa = *(const ushort4*)(Wp + k);
                const ushort4 wb = *(const ushort4*)(Wp + k + 4);
                acc += src[k] * bf2f(wa.x) + src[k + 1] * bf2f(wa.y)
                     + src[k + 2] * bf2f(wa.z) + src[k + 3] * bf2f(wa.w)
                     + src[k + 4] * bf2f(wb.x) + src[k + 5] * bf2f(wb.y)
                     + src[k + 6] * bf2f(wb.z) + src[k + 7] * bf2f(wb.w);
            }
        } else {
            const float* Wp = (const float*)W + n * ld + koff;
#pragma unroll 4
            for (int k = 0; k < 128; k += 4) {
                const float4 w4 = *(const float4*)(Wp + k);
                acc += src[k] * w4.x + src[k + 1] * w4.y + src[k + 2] * w4.z + src[k + 3] * w4.w;
            }
        }
        if (bias) acc += ldF(bias, n, bf);
    }
    outp[oidx] = acc;
}

// ---------------------------------------------------------------------------
// K1: INP precompute — the entire state-independent input_data path, hoisted
// OFF the serial scan: INP[t][row][col] = q_emb[row,t,:]@W1[col,:128]
//   + cW1p[c] + sdQ.W1[sd] + qdQ.W1[qd] + b1, stored bf16.
// Fully parallel: 500 t x 16 rowchunks, one wave each, 32 MFMA per block.
// ---------------------------------------------------------------------------
__global__ void dimkt_inp(const void* __restrict__ q_emb,
                          const void* __restrict__ W1, const void* __restrict__ b1,
                          const int* __restrict__ cI, const int* __restrict__ sI,
                          const int* __restrict__ qI,
                          const float* __restrict__ cW1p, const float* __restrict__ sdQ,
                          const float* __restrict__ qdQ, u16* __restrict__ INP16) {
    const bool bf = detect_bf16(q_emb);
    const int t = blockIdx.x, rc = blockIdx.y;
    const int lane = threadIdx.x, quad = lane >> 4, l15 = lane & 15;
    // A fragments: row = rc*16 + l15 (same lane mapping as the scan's ae)
    bf16x8 ae[4];
#pragma unroll
    for (int ks = 0; ks < 4; ++ks)
        ae[ks] = ldfragR(q_emb, ((rc * 16 + l15) * S_LEN + t) * EDIM + ks * 32 + quad * 8, bf);
    int cx[4], sx[4], qx[4];
#pragma unroll
    for (int i = 0; i < 4; ++i) {
        const int off = (rc * 16 + quad * 4 + i) * S_LEN + t;
        cx[i] = iclamp(cI[off], 1000);
        sx[i] = iclamp(sI[off], 101);
        qx[i] = iclamp(qI[off], 101);
    }
#pragma unroll 1
    for (int ct = 0; ct < 8; ++ct) {
        const int col = ct * 16 + l15;
        bf16x8 w[4];
#pragma unroll
        for (int ks = 0; ks < 4; ++ks)
            w[ks] = ldfragR(W1, col * 512 + ks * 32 + quad * 8, bf);
        const float b1c = ldF(b1, col, bf);
        f32x4 acc;
#pragma unroll
        for (int i = 0; i < 4; ++i)
            acc[i] = b1c + cW1p[cx[i] * 128 + col]
                   + sdQ[sx[i] * 256 + col * 2] + qdQ[qx[i] * 256 + col * 2];
#pragma unroll
        for (int ks = 0; ks < 4; ++ks)
            acc = __builtin_amdgcn_mfma_f32_16x16x32_bf16(ae[ks], w[ks], acc, 0, 0, 0);
#pragma unroll
        for (int i = 0; i < 4; ++i)
            INP16[(t * 256 + rc * 16 + quad * 4 + i) * 128 + col] = f2bf(acc[i]);
    }
}

// ---------------------------------------------------------------------------
// K2: fused 500-step scan. 16 WGs x 512 threads (8 waves). Wave wv owns cols
// [16wv,16wv+16). The state-independent input path is PRECOMPUTED (dimkt_inp)
// -> per step only 5 matmuls (Y2,Y3,Y6,Y4,Y5), 4 scalar u16 INP loads, no ae
// pipeline, no cg gather. W6-half tables LDS-resident; idx packed in LDS;
// g=sigm(Y6) computed in phase C (fills as-read latency); Y4/Y5 chains split
// 2+2 to halve MFMA chain latency. Sync: R1-proven LDS spin.
// ---------------------------------------------------------------------------
template <bool BF>
__global__ __launch_bounds__(512, 2) void dimkt_scan(
    const void* __restrict__ q_emb, const u16* __restrict__ INP16,
    const int* __restrict__ cI, const int* __restrict__ sI,
    const int* __restrict__ qI, const int* __restrict__ aI,
    const void* __restrict__ W2, const void* __restrict__ b2,
    const void* __restrict__ W3, const void* __restrict__ b3,
    const void* __restrict__ W4, const void* __restrict__ W5,
    const void* __restrict__ W6, const void* __restrict__ knowledge,
    const float* __restrict__ sdQ, const float* __restrict__ qdQ,
    const float* __restrict__ aW6p, const float* __restrict__ c4t,
    const float* __restrict__ c5t, void* __restrict__ outv) {
    if (detect_bf16(q_emb) != BF) return;   // wrong specialization: uniform exit
    // 136-ushort row stride: 272B = 17*16B -> 16B-aligned ds_read_b128
    __shared__ __align__(16) u16 kbuf[16][136];
    __shared__ __align__(16) u16 qqbuf[16][136];
    __shared__ __align__(16) u16 sdbuf[16][136];
    __shared__ u32 idxL[16][S_LEN];          // packed c|sd|qd|a (32,000 B)
    __shared__ int sctr;
    // dynamic LDS: resident W6-half gather tables (stride 130: bank-spread)
    extern __shared__ __align__(16) u16 dynLDS[];
    u16* sdT = dynLDS;                         // [102][130] bf16 (26,520 B)
    u16* qdT = dynLDS + 102 * 130;             // [102][130]      (26,520 B)
    float* aW6L = (float*)(dynLDS + 2 * 102 * 130); // [2][132] f32 (1,056 B)

    const int tid = threadIdx.x;
    const int wv = tid >> 6, lane = tid & 63;
    const int quad = lane >> 4, l15 = lane & 15;
    const int b0 = blockIdx.x * 16;
    const int col = wv * 16 + l15;             // this thread's output column
    const int col2 = col * 2;

    // ---- stationary weight fragments (registers, 500-step resident) ----
    bf16x8 fW2[4], fW3[4], fW4[4], fW5[4], fW6[4];
#pragma unroll
    for (int ks = 0; ks < 4; ++ks) {
        const int ko = ks * 32 + quad * 8;
        fW2[ks] = ldfragT<BF>(W2, col * 128 + ko);
        fW3[ks] = ldfragT<BF>(W3, col * 128 + ko);
        fW4[ks] = ldfragT<BF>(W4, col * 256 + ko);   // W4[:, :128]
        fW5[ks] = ldfragT<BF>(W5, col * 256 + ko);   // W5[:, :128]
        fW6[ks] = ldfragT<BF>(W6, col * 512 + ko);   // W6[:, :128]
    }
    const float b2v = ldF(b2, col, BF);
    const float b3v = ldF(b3, col, BF);
    const float c4_0 = c4t[col], c4_1 = c4t[128 + col];
    const float c5_0 = c5t[col], c5_1 = c5t[128 + col];

    // ---- pack all per-step indices into LDS (one-time) ----
#pragma unroll 1
    for (int r = 0; r < 16; ++r)
#pragma unroll 1
        for (int t = tid; t < S_LEN; t += 512) {
            const int off = (b0 + r) * S_LEN + t;
            idxL[r][t] = (u32)iclamp(cI[off], 1000)
                       | ((u32)iclamp(sI[off], 101) << 10)
                       | ((u32)iclamp(qI[off], 101) << 17)
                       | ((u32)iclamp(aI[off], 1) << 24);
        }

    // ---- stage resident W6-half tables into LDS (bf16) ----
#pragma unroll 1
    for (int v = tid; v < 102 * 128; v += 512) {
        const int sx = v >> 7, cc = v & 127;
        sdT[sx * 130 + cc] = f2bf(sdQ[sx * 256 + cc * 2 + 1]);
        qdT[sx * 130 + cc] = f2bf(qdQ[sx * 256 + cc * 2 + 1]);
    }
    if (tid < 256) {
        const int rr = tid >> 7, cc = tid & 127;
        aW6L[rr * 132 + cc] = aW6p[rr * 128 + cc];
    }
    if (tid == 0) sctr = 0;
    __syncthreads();                                 // idxL/tables published

    // ---- t=0 init: z6c from f32 tables, qq_0 = k0 - inp_0 (precomputed) ----
    float kold[4], z6c[4], g[4];
    int ac[4];
    {
        const float k0 = ldF(knowledge, col, BF);
        const u16 k0b = f2bf(k0);
#pragma unroll
        for (int i = 0; i < 4; ++i) {
            const u32 p = idxL[quad * 4 + i][0];
            const int sx = (p >> 10) & 127, qx = (p >> 17) & 127, ax = (p >> 24) & 1;
            ac[i] = ax;
            const float2 sgp = *(const float2*)(sdQ + sx * 256 + col2);
            const float2 qgp = *(const float2*)(qdQ + qx * 256 + col2);
            z6c[i] = aW6p[ax * 128 + col] + sgp.y + qgp.y;
            const float inp0 = bf2f(INP16[(0 * 256 + b0 + quad * 4 + i) * 128 + col]);
            kold[i] = k0;
            kbuf[quad * 4 + i][col] = k0b;
            qqbuf[quad * 4 + i][col] = f2bf(k0 - inp0);
        }
    }
    // ---- prime: packed idx(1) ----
    u32 pk4[4];
#pragma unroll
    for (int i = 0; i < 4; ++i) pk4[i] = idxL[quad * 4 + i][1];

    __syncthreads();                                 // t0 kbuf/qqbuf published

    int bar = 0;
#pragma unroll 1
    for (int t = 0; t < S_LEN; ++t) {
        const int tf2 = (t + 2 < S_LEN) ? t + 2 : S_LEN - 1;
        const int tp = (t + 1 < S_LEN) ? t + 1 : S_LEN - 1;
        // ---- unpack idx(t+1); issue inp(t+1) loads (consumed end of C);
        //      resident-table reads for z6(t+1) (static data: no hazard) ----
        int an[4];
        u16 inpN[4];
        float sw6[4], qw6[4], agv[4];
#pragma unroll
        for (int i = 0; i < 4; ++i) {
            const u32 p = pk4[i];
            const int sx = (p >> 10) & 127, qx = (p >> 17) & 127;
            an[i] = (p >> 24) & 1;
            inpN[i] = INP16[(tp * 256 + b0 + quad * 4 + i) * 128 + col];
            sw6[i] = bf2f(sdT[sx * 130 + col]);
            qw6[i] = bf2f(qdT[qx * 130 + col]);
            agv[i] = aW6L[an[i] * 132 + col];
        }
#pragma unroll
        for (int i = 0; i < 4; ++i) pk4[i] = idxL[quad * 4 + i][tf2];

        // ---- phase B: Y2/Y3 on qq, Y6 on k; sdft -> LDS ----
        bf16x8 aq[4], ak[4];
#pragma unroll
        for (int ks = 0; ks < 4; ++ks) {
            aq[ks] = *(const bf16x8*)&qqbuf[l15][ks * 32 + quad * 8];
            ak[ks] = *(const bf16x8*)&kbuf[l15][ks * 32 + quad * 8];
        }
        // split accumulator chains (2+2) to halve MFMA dependency latency
        f32x4 Y2a = (f32x4){b2v, b2v, b2v, b2v}, Y2b = (f32x4){0.f, 0.f, 0.f, 0.f};
        f32x4 Y3a = (f32x4){b3v, b3v, b3v, b3v}, Y3b = (f32x4){0.f, 0.f, 0.f, 0.f};
        f32x4 Y6a = (f32x4){z6c[0], z6c[1], z6c[2], z6c[3]}, Y6b = (f32x4){0.f, 0.f, 0.f, 0.f};
        Y2a = __builtin_amdgcn_mfma_f32_16x16x32_bf16(aq[0], fW2[0], Y2a, 0, 0, 0);
        Y3a = __builtin_amdgcn_mfma_f32_16x16x32_bf16(aq[0], fW3[0], Y3a, 0, 0, 0);
        Y6a = __builtin_amdgcn_mfma_f32_16x16x32_bf16(ak[0], fW6[0], Y6a, 0, 0, 0);
        Y2b = __builtin_amdgcn_mfma_f32_16x16x32_bf16(aq[2], fW2[2], Y2b, 0, 0, 0);
        Y3b = __builtin_amdgcn_mfma_f32_16x16x32_bf16(aq[2], fW3[2], Y3b, 0, 0, 0);
        Y6b = __builtin_amdgcn_mfma_f32_16x16x32_bf16(ak[2], fW6[2], Y6b, 0, 0, 0);
        Y2a = __builtin_amdgcn_mfma_f32_16x16x32_bf16(aq[1], fW2[1], Y2a, 0, 0, 0);
        Y3a = __builtin_amdgcn_mfma_f32_16x16x32_bf16(aq[1], fW3[1], Y3a, 0, 0, 0);
        Y6a = __builtin_amdgcn_mfma_f32_16x16x32_bf16(ak[1], fW6[1], Y6a, 0, 0, 0);
        Y2b = __builtin_amdgcn_mfma_f32_16x16x32_bf16(aq[3], fW2[3], Y2b, 0, 0, 0);
        Y3b = __builtin_amdgcn_mfma_f32_16x16x32_bf16(aq[3], fW3[3], Y3b, 0, 0, 0);
        Y6b = __builtin_amdgcn_mfma_f32_16x16x32_bf16(ak[3], fW6[3], Y6b, 0, 0, 0);
        f32x4 Y2 = Y2a + Y2b, Y3 = Y3a + Y3b, Y6 = Y6a + Y6b;
        float sdv[4];
#pragma unroll
        for (int i = 0; i < 4; ++i) sdv[i] = sigm(Y2[i]) * tanh_(Y3[i]);
        {
            const u32 s01 = cvtpk(sdv[0], sdv[1]), s23 = cvtpk(sdv[2], sdv[3]);
            sdbuf[quad * 4 + 0][col] = (u16)s01;
            sdbuf[quad * 4 + 1][col] = (u16)(s01 >> 16);
            sdbuf[quad * 4 + 2][col] = (u16)s23;
            sdbuf[quad * 4 + 3][col] = (u16)(s23 >> 16);
        }
        bar += 8; wgsync(&sctr, bar);

        // ---- phase C: Y4/Y5 on sdft; g here (fills as-read latency);
        //      k update; write k/qq for t+1 ----
        bf16x8 as[4];
#pragma unroll
        for (int ks = 0; ks < 4; ++ks)
            as[ks] = *(const bf16x8*)&sdbuf[l15][ks * 32 + quad * 8];
#pragma unroll
        for (int i = 0; i < 4; ++i) g[i] = sigm(Y6[i]);
        f32x4 Y4a = (f32x4){ac[0] ? c4_1 : c4_0, ac[1] ? c4_1 : c4_0,
                            ac[2] ? c4_1 : c4_0, ac[3] ? c4_1 : c4_0};
        f32x4 Y5a = (f32x4){ac[0] ? c5_1 : c5_0, ac[1] ? c5_1 : c5_0,
                            ac[2] ? c5_1 : c5_0, ac[3] ? c5_1 : c5_0};
        f32x4 Y4b = (f32x4){0.f, 0.f, 0.f, 0.f}, Y5b = (f32x4){0.f, 0.f, 0.f, 0.f};
        Y4a = __builtin_amdgcn_mfma_f32_16x16x32_bf16(as[0], fW4[0], Y4a, 0, 0, 0);
        Y5a = __builtin_amdgcn_mfma_f32_16x16x32_bf16(as[0], fW5[0], Y5a, 0, 0, 0);
        Y4b = __builtin_amdgcn_mfma_f32_16x16x32_bf16(as[2], fW4[2], Y4b, 0, 0, 0);
        Y5b = __builtin_amdgcn_mfma_f32_16x16x32_bf16(as[2], fW5[2], Y5b, 0, 0, 0);
        Y4a = __builtin_amdgcn_mfma_f32_16x16x32_bf16(as[1], fW4[1], Y4a, 0, 0, 0);
        Y5a = __builtin_amdgcn_mfma_f32_16x16x32_bf16(as[1], fW5[1], Y5a, 0, 0, 0);
        Y4b = __builtin_amdgcn_mfma_f32_16x16x32_bf16(as[3], fW4[3], Y4b, 0, 0, 0);
        Y5b = __builtin_amdgcn_mfma_f32_16x16x32_bf16(as[3], fW5[3], Y5b, 0, 0, 0);
        const f32x4 Y4 = Y4a + Y4b, Y5 = Y5a + Y5b;
        float knA[4], qqA[4];
#pragma unroll
        for (int i = 0; i < 4; ++i) {
            const float pk = sigm(Y4[i]) * tanh_(Y5[i]);
            const float kn = g[i] * kold[i] + (1.0f - g[i]) * pk;
            kold[i] = kn; knA[i] = kn;
            qqA[i] = kn - bf2f(inpN[i]);             // qq_{t+1}
        }
        {
            const u32 k01 = cvtpk(knA[0], knA[1]), k23 = cvtpk(knA[2], knA[3]);
            const u32 q01 = cvtpk(qqA[0], qqA[1]), q23 = cvtpk(qqA[2], qqA[3]);
            kbuf[quad * 4 + 0][col] = (u16)k01;
            kbuf[quad * 4 + 1][col] = (u16)(k01 >> 16);
            kbuf[quad * 4 + 2][col] = (u16)k23;
            kbuf[quad * 4 + 3][col] = (u16)(k23 >> 16);
            qqbuf[quad * 4 + 0][col] = (u16)q01;
            qqbuf[quad * 4 + 1][col] = (u16)(q01 >> 16);
            qqbuf[quad * 4 + 2][col] = (u16)q23;
            qqbuf[quad * 4 + 3][col] = (u16)(q23 >> 16);
        }
        // ---- rotate: z6 for t+1 ----
#pragma unroll
        for (int i = 0; i < 4; ++i) {
            z6c[i] = agv[i] + sw6[i] + qw6[i];
            ac[i] = an[i];
        }
        bar += 8; wgsync(&sctr, bar);
    }

    // ---- epilogue: out = sigmoid(k_final), [B][E], dtype matches input ----
#pragma unroll
    for (int i = 0; i < 4; ++i) {
        const int row = quad * 4 + i;
        const float v = sigm(kold[i]);
        const int off = (b0 + row) * EDIM + col;
        if (BF) ((u16*)outv)[off] = f2bf(v);
        else    ((float*)outv)[off] = v;
    }
}

// ---------------------------------------------------------------------------
extern "C" void kernel_launch(void* const* d_in, const int* in_sizes, int n_in,
                              void* d_out, int out_size, void* d_ws, size_t ws_size,
                              hipStream_t stream) {
    static const int exp_sizes[27] = {
        128000, 128000, 128000, 128000, 128000,
        128000, 128000, 128000, 128000,
        16384000,
        128128, 13056, 13056, 256, 128,
        65536, 128, 16384, 128, 16384, 128,
        32768, 128, 32768, 128, 65536, 128
    };
    bool sizes_ok = (n_in == 27) && (out_size == 32768);
    if (sizes_ok)
        for (int i = 0; i < 27; ++i)
            if (in_sizes[i] != exp_sizes[i]) { sizes_ok = false; break; }
    if (!sizes_ok) {
        dimkt_sentinel<<<dim3(128), dim3(256), 0, stream>>>((u16*)d_out, (u16)0xC080); // -4.0
        return;
    }
    const size_t WS_NEED = 724480;                   // f32 tables
    const size_t WS_NEED16 = WS_NEED + 32768000u;    // + INP16 (proven available: R4/R5 used it)
    if (ws_size < WS_NEED16) {
        dimkt_sentinel<<<dim3(128), dim3(256), 0, stream>>>((u16*)d_out, (u16)0x4110); // 9.0
        return;
    }

    const int* c   = (const int*)d_in[1];
    const int* sd  = (const int*)d_in[2];
    const int* qd  = (const int*)d_in[3];
    const int* a   = (const int*)d_in[4];
    const void* q_emb = d_in[9];
    const void* c_tab = d_in[10];
    const void* sd_tab = d_in[11];
    const void* qd_tab = d_in[12];
    const void* a_tab = d_in[13];
    const void* knowledge = d_in[14];
    const void* W1 = d_in[15]; const void* b1 = d_in[16];
    const void* W2 = d_in[17]; const void* b2 = d_in[18];
    const void* W3 = d_in[19]; const void* b3 = d_in[20];
    const void* W4 = d_in[21]; const void* b4 = d_in[22];
    const void* W5 = d_in[23]; const void* b5 = d_in[24];
    const void* W6 = d_in[25]; const void* b6 = d_in[26];

    float* wsf = (float*)d_ws;
    float* cW1p = wsf;                 // 1001*128
    float* sdQ  = wsf + 128128;        // 102*256
    float* qdQ  = wsf + 154240;        // 102*256
    float* aW6p = wsf + 180352;        // 2*128 (+b6)
    float* c4t  = wsf + 180608;        // 2*128 (+b4)
    float* c5t  = wsf + 180864;        // 2*128 (+b5), ends at 181120 floats
    u16* INP16  = (u16*)((char*)d_ws + WS_NEED);     // 500*256*128 bf16

    // dynamic LDS: 2 tables [102][130] bf16 + aW6L [2][132] f32
    constexpr int DYN_BYTES = 2 * 102 * 130 * 2 + 2 * 132 * 4;   // 54,096 B
    hipFuncSetAttribute(reinterpret_cast<const void*>(&dimkt_scan<true>),
                        hipFuncAttributeMaxDynamicSharedMemorySize, DYN_BYTES);
    hipFuncSetAttribute(reinterpret_cast<const void*>(&dimkt_scan<false>),
                        hipFuncAttributeMaxDynamicSharedMemorySize, DYN_BYTES);

    dimkt_tabs<<<dim3(1415), dim3(128), 0, stream>>>(
        q_emb, c_tab, sd_tab, qd_tab, a_tab, W1, W4, W5, W6, b4, b5, b6,
        cW1p, sdQ, qdQ, aW6p, c4t, c5t);

    dimkt_inp<<<dim3(500, 16), dim3(64), 0, stream>>>(
        q_emb, W1, b1, c, sd, qd, cW1p, sdQ, qdQ, INP16);

    dimkt_scan<true><<<dim3(16), dim3(512), DYN_BYTES, stream>>>(
        q_emb, INP16, c, sd, qd, a, W2, b2, W3, b3, W4, W5, W6, knowledge,
        sdQ, qdQ, aW6p, c4t, c5t, d_out);
    dimkt_scan<false><<<dim3(16), dim3(512), DYN_BYTES, stream>>>(
        q_emb, INP16, c, sd, qd, a, W2, b2, W3, b3, W4, W5, W6, knowledge,
        sdQ, qdQ, aW6p, c4t, c5t, d_out);
}

// Round 7
// 998.350 us; speedup vs baseline: 2.0332x; 1.0319x over previous
//
#include <hip/hip_runtime.h>

typedef unsigned short u16;
typedef unsigned int u32;
typedef short bf16x8 __attribute__((ext_vector_type(8)));
typedef float f32x4 __attribute__((ext_vector_type(4)));

#define S_LEN 500
#define NB 256
#define EDIM 128

__device__ __forceinline__ float bf2f(u16 u) { return __uint_as_float(((u32)u) << 16); }
__device__ __forceinline__ u16 f2bf(float f) {
    u32 x = __float_as_uint(f);
    x += 0x7FFFu + ((x >> 16) & 1u);   // round-to-nearest-even
    return (u16)(x >> 16);
}
// HW packed f32->bf16 (RNE, matches f2bf): 1 inst for 2 values. lo->bits[15:0].
__device__ __forceinline__ u32 cvtpk(float lo, float hi) {
    u32 r;
    asm("v_cvt_pk_bf16_f32 %0, %1, %2" : "=v"(r) : "v"(lo), "v"(hi));
    return r;
}
__device__ __forceinline__ float fexp(float x) { return __builtin_amdgcn_exp2f(x * 1.44269504089f); }
__device__ __forceinline__ float frcp(float x) { return __builtin_amdgcn_rcpf(x); }
__device__ __forceinline__ float sigm(float x) { return frcp(1.0f + fexp(-x)); }
__device__ __forceinline__ float tanh_(float x) { return 1.0f - 2.0f * frcp(1.0f + fexp(2.0f * x)); }
__device__ __forceinline__ int iclamp(int v, int hi) { return v < 0 ? 0 : (v > hi ? hi : v); }

// ---------------------------------------------------------------------------
// R1-proven workgroup sync: lane-0 atomicAdd on an LDS counter + broadcast
// poll. Measured FASTER than raw s_barrier on this kernel (1490 vs 1878 us)
// -- staggered release naturally de-synchronizes the 2 waves/SIMD bursts.
// ---------------------------------------------------------------------------
__device__ __forceinline__ void wgsync(volatile int* c, int target) {
    __asm__ volatile("s_waitcnt lgkmcnt(0)" ::: "memory");  // prior LDS writes done
    if ((threadIdx.x & 63) == 0) atomicAdd((int*)c, 1);
    while (*c < target) {}
    __asm__ volatile("" ::: "memory");
}

// ---------------------------------------------------------------------------
// Runtime float-dtype detection from q_embedding bit patterns (wave-uniform).
// ---------------------------------------------------------------------------
__device__ __forceinline__ bool detect_bf16(const void* q) {
    const u16* w = (const u16*)q;
    int plaus = 0;
#pragma unroll 1
    for (int i = 0; i < 64; ++i) {
        const u16 v = w[2 * i];
        const int e = (v >> 7) & 0xFF;
        plaus += (v == 0 || (e >= 100 && e <= 130)) ? 1 : 0;
    }
    return plaus >= 48;
}
__device__ __forceinline__ float ldF(const void* p, int i, bool bf) {
    return bf ? bf2f(((const u16*)p)[i]) : ((const float*)p)[i];
}
template <bool BF>
__device__ __forceinline__ bf16x8 ldfragT(const void* p, int i) {
    if (BF) return *(const bf16x8*)((const u16*)p + i);
    const float* f = (const float*)p + i;
    bf16x8 r;
#pragma unroll
    for (int e = 0; e < 8; ++e) r[e] = (short)f2bf(f[e]);
    return r;
}
// runtime-dtype fragment loader (wave-uniform bf flag)
__device__ __forceinline__ bf16x8 ldfragR(const void* p, int i, bool bf) {
    if (bf) return *(const bf16x8*)((const u16*)p + i);
    const float* f = (const float*)p + i;
    bf16x8 r;
#pragma unroll
    for (int e = 0; e < 8; ++e) r[e] = (short)f2bf(f[e]);
    return r;
}

__global__ void dimkt_sentinel(u16* __restrict__ out, u16 val) {
    out[blockIdx.x * 256 + threadIdx.x] = val;
}

// ---------------------------------------------------------------------------
// K-conv: one-time q_emb f32 -> bf16 (guarded: no-op when input is bf16).
// ---------------------------------------------------------------------------
__global__ void dimkt_qe16(const float* __restrict__ qf, u16* __restrict__ qe16) {
    if (detect_bf16(qf)) return;
    const int i = (blockIdx.x * 256 + threadIdx.x) * 8;
    const float4 a = *(const float4*)(qf + i);
    const float4 b = *(const float4*)(qf + i + 4);
    ushort4 lo, hi;
    lo.x = f2bf(a.x); lo.y = f2bf(a.y); lo.z = f2bf(a.z); lo.w = f2bf(a.w);
    hi.x = f2bf(b.x); hi.y = f2bf(b.y); hi.z = f2bf(b.z); hi.w = f2bf(b.w);
    *(ushort4*)(qe16 + i) = lo;
    *(ushort4*)(qe16 + i + 4) = hi;
}

// K-conv: W1 -> bf16 (or copy if already bf16). 128*512 = 65,536 elems.
__global__ void dimkt_w1bf(const void* __restrict__ W1, const void* __restrict__ qref,
                           u16* __restrict__ W1b) {
    const bool bf = detect_bf16(qref);
    const int i = blockIdx.x * 256 + threadIdx.x;
    W1b[i] = bf ? ((const u16*)W1)[i] : f2bf(((const float*)W1)[i]);
}

// ---------------------------------------------------------------------------
// K0: tiny gather-table precompute. Layout (per-col scalar):
//   cW1p[cx*128 + col] ; sdQ/qdQ[x*256 + col*2 + {0:W1,1:W6}]
//   aW6p[ax*128 + col] (+b6) ; c4t/c5t[ax*128 + col] (+b4/+b5)
// ---------------------------------------------------------------------------
__global__ void dimkt_tabs(const void* __restrict__ q_emb,
                           const void* __restrict__ c_tab, const void* __restrict__ sd_tab,
                           const void* __restrict__ qd_tab, const void* __restrict__ a_tab,
                           const void* __restrict__ W1, const void* __restrict__ W4,
                           const void* __restrict__ W5, const void* __restrict__ W6,
                           const void* __restrict__ b4, const void* __restrict__ b5,
                           const void* __restrict__ b6,
                           float* __restrict__ cW1p, float* __restrict__ sdQ,
                           float* __restrict__ qdQ, float* __restrict__ aW6p,
                           float* __restrict__ c4t, float* __restrict__ c5t) {
    const bool bf = detect_bf16(q_emb);
    __shared__ float src[128];
    const int r = blockIdx.x, n = threadIdx.x;
    const void* srcp; const void* W; const void* bias = nullptr;
    int soff, koff, ld, oidx; float* outp; bool mask;
    if (r < 1001)      { srcp = c_tab;  soff = r * 128;               W = W1; koff = 128; ld = 512; outp = cW1p; oidx = r * 128 + n;           mask = (r == 0); }
    else if (r < 1103) { int rr = r - 1001; srcp = sd_tab; soff = rr * 128; W = W1; koff = 256; ld = 512; outp = sdQ;  oidx = rr * 256 + n * 2;     mask = (rr == 0); }
    else if (r < 1205) { int rr = r - 1103; srcp = qd_tab; soff = rr * 128; W = W1; koff = 384; ld = 512; outp = qdQ;  oidx = rr * 256 + n * 2;     mask = (rr == 0); }
    else if (r < 1307) { int rr = r - 1205; srcp = sd_tab; soff = rr * 128; W = W6; koff = 256; ld = 512; outp = sdQ;  oidx = rr * 256 + n * 2 + 1; mask = (rr == 0); }
    else if (r < 1409) { int rr = r - 1307; srcp = qd_tab; soff = rr * 128; W = W6; koff = 384; ld = 512; outp = qdQ;  oidx = rr * 256 + n * 2 + 1; mask = (rr == 0); }
    else if (r < 1411) { int rr = r - 1409; srcp = a_tab;  soff = rr * 128; W = W6; koff = 128; ld = 512; outp = aW6p; oidx = rr * 128 + n;         bias = b6; mask = false; }
    else if (r < 1413) { int rr = r - 1411; srcp = a_tab;  soff = rr * 128; W = W4; koff = 128; ld = 256; outp = c4t;  oidx = rr * 128 + n;         bias = b4; mask = false; }
    else               { int rr = r - 1413; srcp = a_tab;  soff = rr * 128; W = W5; koff = 128; ld = 256; outp = c5t;  oidx = rr * 128 + n;         bias = b5; mask = false; }
    src[n] = ldF(srcp, soff + n, bf);
    __syncthreads();
    float acc = 0.f;
    if (!mask) {
        if (bf) {
            const u16* Wp = (const u16*)W + n * ld + koff;
#pragma unroll 4
            for (int k = 0; k < 128; k += 8) {
                const ushort4 wa = *(const ushort4*)(Wp + k);
                const ushort4 wb = *(const ushort4*)(Wp + k + 4);
                acc += src[k] * bf2f(wa.x) + src[k + 1] * bf2f(wa.y)
                     + src[k + 2] * bf2f(wa.z) + src[k + 3] * bf2f(wa.w)
                     + src[k + 4] * bf2f(wb.x) + src[k + 5] * bf2f(wb.y)
                     + src[k + 6] * bf2f(wb.z) + src[k + 7] * bf2f(wb.w);
            }
        } else {
            const float* Wp = (const float*)W + n * ld + koff;
#pragma unroll 4
            for (int k = 0; k < 128; k += 4) {
                const float4 w4 = *(const float4*)(Wp + k);
                acc += src[k] * w4.x + src[k + 1] * w4.y + src[k + 2] * w4.z + src[k + 3] * w4.w;
            }
        }
        if (bias) acc += ldF(bias, n, bf);
    }
    outp[oidx] = acc;
}

// ---------------------------------------------------------------------------
// K1: INP(+Z6) precompute. pk=1: store u32 {inp(bf16 lo), z6(bf16 hi)} in
// TRANSPOSED layout INPZ6T[(t*128+col)*256 + row] -> the scan fetches its 4
// rows with ONE dwordx4 per step. pk=0: R6-style bf16 INP16 row-major.
// fastpath=1: ae/W1 fragments from pre-converted bf16 (vector loads).
// ---------------------------------------------------------------------------
__global__ void dimkt_inp(const void* __restrict__ q_emb, const u16* __restrict__ qe16,
                          const u16* __restrict__ W1b, const int fastpath,
                          const void* __restrict__ W1, const void* __restrict__ b1,
                          const int* __restrict__ cI, const int* __restrict__ sI,
                          const int* __restrict__ qI, const int* __restrict__ aI,
                          const float* __restrict__ cW1p, const float* __restrict__ sdQ,
                          const float* __restrict__ qdQ, const float* __restrict__ aW6p,
                          u16* __restrict__ INP16, u32* __restrict__ INPZ6T, const int pk) {
    const bool bf = detect_bf16(q_emb);
    const int t = blockIdx.x, rc = blockIdx.y;
    const int lane = threadIdx.x, quad = lane >> 4, l15 = lane & 15;
    const bool fA = bf || (fastpath != 0);
    const u16* aes = bf ? (const u16*)q_emb : qe16;
    bf16x8 ae[4];
#pragma unroll
    for (int ks = 0; ks < 4; ++ks) {
        const int off = ((rc * 16 + l15) * S_LEN + t) * EDIM + ks * 32 + quad * 8;
        ae[ks] = fA ? *(const bf16x8*)(aes + off) : ldfragR(q_emb, off, false);
    }
    int cx[4], sx[4], qx[4], ax[4];
#pragma unroll
    for (int i = 0; i < 4; ++i) {
        const int off = (rc * 16 + quad * 4 + i) * S_LEN + t;
        cx[i] = iclamp(cI[off], 1000);
        sx[i] = iclamp(sI[off], 101);
        qx[i] = iclamp(qI[off], 101);
        ax[i] = iclamp(aI[off], 1);
    }
#pragma unroll 1
    for (int ct = 0; ct < 8; ++ct) {
        const int colc = ct * 16 + l15;
        bf16x8 w[4];
#pragma unroll
        for (int ks = 0; ks < 4; ++ks) {
            const int woff = colc * 512 + ks * 32 + quad * 8;
            w[ks] = fastpath ? *(const bf16x8*)(W1b + woff) : ldfragR(W1, woff, bf);
        }
        const float b1c = ldF(b1, colc, bf);
        f32x4 acc; float z6v[4];
#pragma unroll
        for (int i = 0; i < 4; ++i) {
            const float2 sgp = *(const float2*)(sdQ + sx[i] * 256 + colc * 2);
            const float2 qgp = *(const float2*)(qdQ + qx[i] * 256 + colc * 2);
            acc[i] = b1c + cW1p[cx[i] * 128 + colc] + sgp.x + qgp.x;
            z6v[i] = pk ? (aW6p[ax[i] * 128 + colc] + sgp.y + qgp.y) : 0.f;
        }
#pragma unroll
        for (int ks = 0; ks < 4; ++ks)
            acc = __builtin_amdgcn_mfma_f32_16x16x32_bf16(ae[ks], w[ks], acc, 0, 0, 0);
        if (pk) {
            uint4 st;
            st.x = cvtpk(acc[0], z6v[0]); st.y = cvtpk(acc[1], z6v[1]);
            st.z = cvtpk(acc[2], z6v[2]); st.w = cvtpk(acc[3], z6v[3]);
            *(uint4*)(INPZ6T + ((size_t)t * 128 + colc) * 256 + rc * 16 + quad * 4) = st;
        } else {
#pragma unroll
            for (int i = 0; i < 4; ++i)
                INP16[((size_t)t * 256 + rc * 16 + quad * 4 + i) * 128 + colc] = f2bf(acc[i]);
        }
    }
}

// ---------------------------------------------------------------------------
// K2-PK: fused 500-step scan, packed-input form. 16 WGs x 512 threads.
// Per step per thread: ONE dwordx4 {inp,z6}x4 + 4 aI dword loads, 12 LDS
// b128 reads, 20 MFMA, elementwise chains, 12 u16 ds_writes, 2 spins.
// No LDS tables, no idx unpack, no z6 summation -> ~50 fewer VALU ops and
// ~16 fewer LDS ops per thread per step vs the R6 form.
// ---------------------------------------------------------------------------
template <bool BF>
__global__ __launch_bounds__(512, 2) void dimkt_scan_pk(
    const void* __restrict__ q_emb, const u32* __restrict__ INPZ6T,
    const int* __restrict__ aI,
    const void* __restrict__ W2, const void* __restrict__ b2,
    const void* __restrict__ W3, const void* __restrict__ b3,
    const void* __restrict__ W4, const void* __restrict__ W5,
    const void* __restrict__ W6, const void* __restrict__ knowledge,
    const float* __restrict__ c4t, const float* __restrict__ c5t,
    void* __restrict__ outv) {
    if (detect_bf16(q_emb) != BF) return;   // wrong specialization: uniform exit
    __shared__ __align__(16) u16 kbuf[16][136];
    __shared__ __align__(16) u16 qqbuf[16][136];
    __shared__ __align__(16) u16 sdbuf[16][136];
    __shared__ int sctr;

    const int tid = threadIdx.x;
    const int wv = tid >> 6, lane = tid & 63;
    const int quad = lane >> 4, l15 = lane & 15;
    const int b0 = blockIdx.x * 16;
    const int col = wv * 16 + l15;

    // ---- stationary weight fragments (registers, 500-step resident) ----
    bf16x8 fW2[4], fW3[4], fW4[4], fW5[4], fW6[4];
#pragma unroll
    for (int ks = 0; ks < 4; ++ks) {
        const int ko = ks * 32 + quad * 8;
        fW2[ks] = ldfragT<BF>(W2, col * 128 + ko);
        fW3[ks] = ldfragT<BF>(W3, col * 128 + ko);
        fW4[ks] = ldfragT<BF>(W4, col * 256 + ko);   // W4[:, :128]
        fW5[ks] = ldfragT<BF>(W5, col * 256 + ko);   // W5[:, :128]
        fW6[ks] = ldfragT<BF>(W6, col * 512 + ko);   // W6[:, :128]
    }
    const float b2v = ldF(b2, col, BF);
    const float b3v = ldF(b3, col, BF);
    const float c4_0 = c4t[col], c4_1 = c4t[128 + col];
    const float c5_0 = c5t[col], c5_1 = c5t[128 + col];

    const u32* pzBase = INPZ6T + (size_t)col * 256 + b0 + quad * 4;
    const int aRow = (b0 + quad * 4) * S_LEN;

    // ---- t=0 init ----
    float kold[4], z6c[4], g[4];
    int ac[4];
    {
        const float k0 = ldF(knowledge, col, BF);
        const u16 k0b = f2bf(k0);
        const uint4 pz0 = *(const uint4*)pzBase;
        const u32 pzv[4] = {pz0.x, pz0.y, pz0.z, pz0.w};
        if (tid == 0) sctr = 0;
#pragma unroll
        for (int i = 0; i < 4; ++i) {
            ac[i] = iclamp(aI[aRow + i * S_LEN], 1);
            z6c[i] = __uint_as_float(pzv[i] & 0xFFFF0000u);
            const float inp0 = __uint_as_float(pzv[i] << 16);
            kold[i] = k0;
            kbuf[quad * 4 + i][col] = k0b;
            qqbuf[quad * 4 + i][col] = f2bf(k0 - inp0);
        }
    }
    __syncthreads();   // one real barrier pre-loop

    int bar = 0;
#pragma unroll 1
    for (int t = 0; t < S_LEN; ++t) {
        const int tp = (t + 1 < S_LEN) ? t + 1 : S_LEN - 1;
        // ---- prefetch t+1: a-bits + packed {inp,z6} (one dwordx4) ----
        int an[4];
#pragma unroll
        for (int i = 0; i < 4; ++i) an[i] = iclamp(aI[aRow + i * S_LEN + tp], 1);
        const uint4 pzN = *(const uint4*)(pzBase + (size_t)tp * 32768);

        // ---- phase B: Y2/Y3 on qq, Y6 on k; sdft -> LDS ----
        bf16x8 aq[4], ak[4];
#pragma unroll
        for (int ks = 0; ks < 4; ++ks) {
            aq[ks] = *(const bf16x8*)&qqbuf[l15][ks * 32 + quad * 8];
            ak[ks] = *(const bf16x8*)&kbuf[l15][ks * 32 + quad * 8];
        }
        f32x4 Y2a = (f32x4){b2v, b2v, b2v, b2v}, Y2b = (f32x4){0.f, 0.f, 0.f, 0.f};
        f32x4 Y3a = (f32x4){b3v, b3v, b3v, b3v}, Y3b = (f32x4){0.f, 0.f, 0.f, 0.f};
        f32x4 Y6a = (f32x4){z6c[0], z6c[1], z6c[2], z6c[3]}, Y6b = (f32x4){0.f, 0.f, 0.f, 0.f};
        Y2a = __builtin_amdgcn_mfma_f32_16x16x32_bf16(aq[0], fW2[0], Y2a, 0, 0, 0);
        Y3a = __builtin_amdgcn_mfma_f32_16x16x32_bf16(aq[0], fW3[0], Y3a, 0, 0, 0);
        Y6a = __builtin_amdgcn_mfma_f32_16x16x32_bf16(ak[0], fW6[0], Y6a, 0, 0, 0);
        Y2b = __builtin_amdgcn_mfma_f32_16x16x32_bf16(aq[2], fW2[2], Y2b, 0, 0, 0);
        Y3b = __builtin_amdgcn_mfma_f32_16x16x32_bf16(aq[2], fW3[2], Y3b, 0, 0, 0);
        Y6b = __builtin_amdgcn_mfma_f32_16x16x32_bf16(ak[2], fW6[2], Y6b, 0, 0, 0);
        Y2a = __builtin_amdgcn_mfma_f32_16x16x32_bf16(aq[1], fW2[1], Y2a, 0, 0, 0);
        Y3a = __builtin_amdgcn_mfma_f32_16x16x32_bf16(aq[1], fW3[1], Y3a, 0, 0, 0);
        Y6a = __builtin_amdgcn_mfma_f32_16x16x32_bf16(ak[1], fW6[1], Y6a, 0, 0, 0);
        Y2b = __builtin_amdgcn_mfma_f32_16x16x32_bf16(aq[3], fW2[3], Y2b, 0, 0, 0);
        Y3b = __builtin_amdgcn_mfma_f32_16x16x32_bf16(aq[3], fW3[3], Y3b, 0, 0, 0);
        Y6b = __builtin_amdgcn_mfma_f32_16x16x32_bf16(ak[3], fW6[3], Y6b, 0, 0, 0);
        const f32x4 Y2 = Y2a + Y2b, Y3 = Y3a + Y3b, Y6 = Y6a + Y6b;
        float sdv[4];
#pragma unroll
        for (int i = 0; i < 4; ++i) sdv[i] = sigm(Y2[i]) * tanh_(Y3[i]);
        {
            const u32 s01 = cvtpk(sdv[0], sdv[1]), s23 = cvtpk(sdv[2], sdv[3]);
            sdbuf[quad * 4 + 0][col] = (u16)s01;
            sdbuf[quad * 4 + 1][col] = (u16)(s01 >> 16);
            sdbuf[quad * 4 + 2][col] = (u16)s23;
            sdbuf[quad * 4 + 3][col] = (u16)(s23 >> 16);
        }
        bar += 8; wgsync(&sctr, bar);

        // ---- phase C: Y4/Y5 on sdft; g; k update; write k/qq for t+1 ----
        bf16x8 as[4];
#pragma unroll
        for (int ks = 0; ks < 4; ++ks)
            as[ks] = *(const bf16x8*)&sdbuf[l15][ks * 32 + quad * 8];
#pragma unroll
        for (int i = 0; i < 4; ++i) g[i] = sigm(Y6[i]);
        f32x4 Y4a = (f32x4){ac[0] ? c4_1 : c4_0, ac[1] ? c4_1 : c4_0,
                            ac[2] ? c4_1 : c4_0, ac[3] ? c4_1 : c4_0};
        f32x4 Y5a = (f32x4){ac[0] ? c5_1 : c5_0, ac[1] ? c5_1 : c5_0,
                            ac[2] ? c5_1 : c5_0, ac[3] ? c5_1 : c5_0};
        f32x4 Y4b = (f32x4){0.f, 0.f, 0.f, 0.f}, Y5b = (f32x4){0.f, 0.f, 0.f, 0.f};
        Y4a = __builtin_amdgcn_mfma_f32_16x16x32_bf16(as[0], fW4[0], Y4a, 0, 0, 0);
        Y5a = __builtin_amdgcn_mfma_f32_16x16x32_bf16(as[0], fW5[0], Y5a, 0, 0, 0);
        Y4b = __builtin_amdgcn_mfma_f32_16x16x32_bf16(as[2], fW4[2], Y4b, 0, 0, 0);
        Y5b = __builtin_amdgcn_mfma_f32_16x16x32_bf16(as[2], fW5[2], Y5b, 0, 0, 0);
        Y4a = __builtin_amdgcn_mfma_f32_16x16x32_bf16(as[1], fW4[1], Y4a, 0, 0, 0);
        Y5a = __builtin_amdgcn_mfma_f32_16x16x32_bf16(as[1], fW5[1], Y5a, 0, 0, 0);
        Y4b = __builtin_amdgcn_mfma_f32_16x16x32_bf16(as[3], fW4[3], Y4b, 0, 0, 0);
        Y5b = __builtin_amdgcn_mfma_f32_16x16x32_bf16(as[3], fW5[3], Y5b, 0, 0, 0);
        const f32x4 Y4 = Y4a + Y4b, Y5 = Y5a + Y5b;
        const u32 pzv[4] = {pzN.x, pzN.y, pzN.z, pzN.w};
        float knA[4], qqA[4];
#pragma unroll
        for (int i = 0; i < 4; ++i) {
            const float pk = sigm(Y4[i]) * tanh_(Y5[i]);
            const float kn = g[i] * kold[i] + (1.0f - g[i]) * pk;
            kold[i] = kn; knA[i] = kn;
            qqA[i] = kn - __uint_as_float(pzv[i] << 16);    // qq_{t+1} = k - inp_{t+1}
        }
        {
            const u32 k01 = cvtpk(knA[0], knA[1]), k23 = cvtpk(knA[2], knA[3]);
            const u32 q01 = cvtpk(qqA[0], qqA[1]), q23 = cvtpk(qqA[2], qqA[3]);
            kbuf[quad * 4 + 0][col] = (u16)k01;
            kbuf[quad * 4 + 1][col] = (u16)(k01 >> 16);
            kbuf[quad * 4 + 2][col] = (u16)k23;
            kbuf[quad * 4 + 3][col] = (u16)(k23 >> 16);
            qqbuf[quad * 4 + 0][col] = (u16)q01;
            qqbuf[quad * 4 + 1][col] = (u16)(q01 >> 16);
            qqbuf[quad * 4 + 2][col] = (u16)q23;
            qqbuf[quad * 4 + 3][col] = (u16)(q23 >> 16);
        }
        // ---- rotate: z6/ac for t+1 (straight from packed load) ----
#pragma unroll
        for (int i = 0; i < 4; ++i) {
            z6c[i] = __uint_as_float(pzv[i] & 0xFFFF0000u);
            ac[i] = an[i];
        }
        bar += 8; wgsync(&sctr, bar);
    }

    // ---- epilogue: out = sigmoid(k_final), [B][E], dtype matches input ----
#pragma unroll
    for (int i = 0; i < 4; ++i) {
        const int row = quad * 4 + i;
        const float v = sigm(kold[i]);
        const int off = (b0 + row) * EDIM + col;
        if (BF) ((u16*)outv)[off] = f2bf(v);
        else    ((float*)outv)[off] = v;
    }
}

// ---------------------------------------------------------------------------
// K2-FB: R6 scan, verbatim (fallback when ws can't hold INPZ6T).
// ---------------------------------------------------------------------------
template <bool BF>
__global__ __launch_bounds__(512, 2) void dimkt_scan_fb(
    const void* __restrict__ q_emb, const u16* __restrict__ INP16,
    const int* __restrict__ cI, const int* __restrict__ sI,
    const int* __restrict__ qI, const int* __restrict__ aI,
    const void* __restrict__ W2, const void* __restrict__ b2,
    const void* __restrict__ W3, const void* __restrict__ b3,
    const void* __restrict__ W4, const void* __restrict__ W5,
    const void* __restrict__ W6, const void* __restrict__ knowledge,
    const float* __restrict__ sdQ, const float* __restrict__ qdQ,
    const float* __restrict__ aW6p, const float* __restrict__ c4t,
    const float* __restrict__ c5t, void* __restrict__ outv) {
    if (detect_bf16(q_emb) != BF) return;
    __shared__ __align__(16) u16 kbuf[16][136];
    __shared__ __align__(16) u16 qqbuf[16][136];
    __shared__ __align__(16) u16 sdbuf[16][136];
    __shared__ u32 idxL[16][S_LEN];
    __shared__ int sctr;
    extern __shared__ __align__(16) u16 dynLDS[];
    u16* sdT = dynLDS;
    u16* qdT = dynLDS + 102 * 130;
    float* aW6L = (float*)(dynLDS + 2 * 102 * 130);

    const int tid = threadIdx.x;
    const int wv = tid >> 6, lane = tid & 63;
    const int quad = lane >> 4, l15 = lane & 15;
    const int b0 = blockIdx.x * 16;
    const int col = wv * 16 + l15;
    const int col2 = col * 2;

    bf16x8 fW2[4], fW3[4], fW4[4], fW5[4], fW6[4];
#pragma unroll
    for (int ks = 0; ks < 4; ++ks) {
        const int ko = ks * 32 + quad * 8;
        fW2[ks] = ldfragT<BF>(W2, col * 128 + ko);
        fW3[ks] = ldfragT<BF>(W3, col * 128 + ko);
        fW4[ks] = ldfragT<BF>(W4, col * 256 + ko);
        fW5[ks] = ldfragT<BF>(W5, col * 256 + ko);
        fW6[ks] = ldfragT<BF>(W6, col * 512 + ko);
    }
    const float b2v = ldF(b2, col, BF);
    const float b3v = ldF(b3, col, BF);
    const float c4_0 = c4t[col], c4_1 = c4t[128 + col];
    const float c5_0 = c5t[col], c5_1 = c5t[128 + col];

#pragma unroll 1
    for (int r = 0; r < 16; ++r)
#pragma unroll 1
        for (int t = tid; t < S_LEN; t += 512) {
            const int off = (b0 + r) * S_LEN + t;
            idxL[r][t] = (u32)iclamp(cI[off], 1000)
                       | ((u32)iclamp(sI[off], 101) << 10)
                       | ((u32)iclamp(qI[off], 101) << 17)
                       | ((u32)iclamp(aI[off], 1) << 24);
        }
#pragma unroll 1
    for (int v = tid; v < 102 * 128; v += 512) {
        const int sx = v >> 7, cc = v & 127;
        sdT[sx * 130 + cc] = f2bf(sdQ[sx * 256 + cc * 2 + 1]);
        qdT[sx * 130 + cc] = f2bf(qdQ[sx * 256 + cc * 2 + 1]);
    }
    if (tid < 256) {
        const int rr = tid >> 7, cc = tid & 127;
        aW6L[rr * 132 + cc] = aW6p[rr * 128 + cc];
    }
    if (tid == 0) sctr = 0;
    __syncthreads();

    float kold[4], z6c[4], g[4];
    int ac[4];
    {
        const float k0 = ldF(knowledge, col, BF);
        const u16 k0b = f2bf(k0);
#pragma unroll
        for (int i = 0; i < 4; ++i) {
            const u32 p = idxL[quad * 4 + i][0];
            const int sx = (p >> 10) & 127, qx = (p >> 17) & 127, ax = (p >> 24) & 1;
            ac[i] = ax;
            const float2 sgp = *(const float2*)(sdQ + sx * 256 + col2);
            const float2 qgp = *(const float2*)(qdQ + qx * 256 + col2);
            z6c[i] = aW6p[ax * 128 + col] + sgp.y + qgp.y;
            const float inp0 = bf2f(INP16[(size_t)(b0 + quad * 4 + i) * 128 + col]);
            kold[i] = k0;
            kbuf[quad * 4 + i][col] = k0b;
            qqbuf[quad * 4 + i][col] = f2bf(k0 - inp0);
        }
    }
    u32 pk4[4];
#pragma unroll
    for (int i = 0; i < 4; ++i) pk4[i] = idxL[quad * 4 + i][1];
    __syncthreads();

    int bar = 0;
#pragma unroll 1
    for (int t = 0; t < S_LEN; ++t) {
        const int tf2 = (t + 2 < S_LEN) ? t + 2 : S_LEN - 1;
        const int tp = (t + 1 < S_LEN) ? t + 1 : S_LEN - 1;
        int an[4];
        u16 inpN[4];
        float sw6[4], qw6[4], agv[4];
#pragma unroll
        for (int i = 0; i < 4; ++i) {
            const u32 p = pk4[i];
            const int sx = (p >> 10) & 127, qx = (p >> 17) & 127;
            an[i] = (p >> 24) & 1;
            inpN[i] = INP16[((size_t)tp * 256 + b0 + quad * 4 + i) * 128 + col];
            sw6[i] = bf2f(sdT[sx * 130 + col]);
            qw6[i] = bf2f(qdT[qx * 130 + col]);
            agv[i] = aW6L[an[i] * 132 + col];
        }
#pragma unroll
        for (int i = 0; i < 4; ++i) pk4[i] = idxL[quad * 4 + i][tf2];

        bf16x8 aq[4], ak[4];
#pragma unroll
        for (int ks = 0; ks < 4; ++ks) {
            aq[ks] = *(const bf16x8*)&qqbuf[l15][ks * 32 + quad * 8];
            ak[ks] = *(const bf16x8*)&kbuf[l15][ks * 32 + quad * 8];
        }
        f32x4 Y2a = (f32x4){b2v, b2v, b2v, b2v}, Y2b = (f32x4){0.f, 0.f, 0.f, 0.f};
        f32x4 Y3a = (f32x4){b3v, b3v, b3v, b3v}, Y3b = (f32x4){0.f, 0.f, 0.f, 0.f};
        f32x4 Y6a = (f32x4){z6c[0], z6c[1], z6c[2], z6c[3]}, Y6b = (f32x4){0.f, 0.f, 0.f, 0.f};
        Y2a = __builtin_amdgcn_mfma_f32_16x16x32_bf16(aq[0], fW2[0], Y2a, 0, 0, 0);
        Y3a = __builtin_amdgcn_mfma_f32_16x16x32_bf16(aq[0], fW3[0], Y3a, 0, 0, 0);
        Y6a = __builtin_amdgcn_mfma_f32_16x16x32_bf16(ak[0], fW6[0], Y6a, 0, 0, 0);
        Y2b = __builtin_amdgcn_mfma_f32_16x16x32_bf16(aq[2], fW2[2], Y2b, 0, 0, 0);
        Y3b = __builtin_amdgcn_mfma_f32_16x16x32_bf16(aq[2], fW3[2], Y3b, 0, 0, 0);
        Y6b = __builtin_amdgcn_mfma_f32_16x16x32_bf16(ak[2], fW6[2], Y6b, 0, 0, 0);
        Y2a = __builtin_amdgcn_mfma_f32_16x16x32_bf16(aq[1], fW2[1], Y2a, 0, 0, 0);
        Y3a = __builtin_amdgcn_mfma_f32_16x16x32_bf16(aq[1], fW3[1], Y3a, 0, 0, 0);
        Y6a = __builtin_amdgcn_mfma_f32_16x16x32_bf16(ak[1], fW6[1], Y6a, 0, 0, 0);
        Y2b = __builtin_amdgcn_mfma_f32_16x16x32_bf16(aq[3], fW2[3], Y2b, 0, 0, 0);
        Y3b = __builtin_amdgcn_mfma_f32_16x16x32_bf16(aq[3], fW3[3], Y3b, 0, 0, 0);
        Y6b = __builtin_amdgcn_mfma_f32_16x16x32_bf16(ak[3], fW6[3], Y6b, 0, 0, 0);
        const f32x4 Y2 = Y2a + Y2b, Y3 = Y3a + Y3b, Y6 = Y6a + Y6b;
        float sdv[4];
#pragma unroll
        for (int i = 0; i < 4; ++i) sdv[i] = sigm(Y2[i]) * tanh_(Y3[i]);
        {
            const u32 s01 = cvtpk(sdv[0], sdv[1]), s23 = cvtpk(sdv[2], sdv[3]);
            sdbuf[quad * 4 + 0][col] = (u16)s01;
            sdbuf[quad * 4 + 1][col] = (u16)(s01 >> 16);
            sdbuf[quad * 4 + 2][col] = (u16)s23;
            sdbuf[quad * 4 + 3][col] = (u16)(s23 >> 16);
        }
        bar += 8; wgsync(&sctr, bar);

        bf16x8 as[4];
#pragma unroll
        for (int ks = 0; ks < 4; ++ks)
            as[ks] = *(const bf16x8*)&sdbuf[l15][ks * 32 + quad * 8];
#pragma unroll
        for (int i = 0; i < 4; ++i) g[i] = sigm(Y6[i]);
        f32x4 Y4a = (f32x4){ac[0] ? c4_1 : c4_0, ac[1] ? c4_1 : c4_0,
                            ac[2] ? c4_1 : c4_0, ac[3] ? c4_1 : c4_0};
        f32x4 Y5a = (f32x4){ac[0] ? c5_1 : c5_0, ac[1] ? c5_1 : c5_0,
                            ac[2] ? c5_1 : c5_0, ac[3] ? c5_1 : c5_0};
        f32x4 Y4b = (f32x4){0.f, 0.f, 0.f, 0.f}, Y5b = (f32x4){0.f, 0.f, 0.f, 0.f};
        Y4a = __builtin_amdgcn_mfma_f32_16x16x32_bf16(as[0], fW4[0], Y4a, 0, 0, 0);
        Y5a = __builtin_amdgcn_mfma_f32_16x16x32_bf16(as[0], fW5[0], Y5a, 0, 0, 0);
        Y4b = __builtin_amdgcn_mfma_f32_16x16x32_bf16(as[2], fW4[2], Y4b, 0, 0, 0);
        Y5b = __builtin_amdgcn_mfma_f32_16x16x32_bf16(as[2], fW5[2], Y5b, 0, 0, 0);
        Y4a = __builtin_amdgcn_mfma_f32_16x16x32_bf16(as[1], fW4[1], Y4a, 0, 0, 0);
        Y5a = __builtin_amdgcn_mfma_f32_16x16x32_bf16(as[1], fW5[1], Y5a, 0, 0, 0);
        Y4b = __builtin_amdgcn_mfma_f32_16x16x32_bf16(as[3], fW4[3], Y4b, 0, 0, 0);
        Y5b = __builtin_amdgcn_mfma_f32_16x16x32_bf16(as[3], fW5[3], Y5b, 0, 0, 0);
        const f32x4 Y4 = Y4a + Y4b, Y5 = Y5a + Y5b;
        float knA[4], qqA[4];
#pragma unroll
        for (int i = 0; i < 4; ++i) {
            const float pk = sigm(Y4[i]) * tanh_(Y5[i]);
            const float kn = g[i] * kold[i] + (1.0f - g[i]) * pk;
            kold[i] = kn; knA[i] = kn;
            qqA[i] = kn - bf2f(inpN[i]);
        }
        {
            const u32 k01 = cvtpk(knA[0], knA[1]), k23 = cvtpk(knA[2], knA[3]);
            const u32 q01 = cvtpk(qqA[0], qqA[1]), q23 = cvtpk(qqA[2], qqA[3]);
            kbuf[quad * 4 + 0][col] = (u16)k01;
            kbuf[quad * 4 + 1][col] = (u16)(k01 >> 16);
            kbuf[quad * 4 + 2][col] = (u16)k23;
            kbuf[quad * 4 + 3][col] = (u16)(k23 >> 16);
            qqbuf[quad * 4 + 0][col] = (u16)q01;
            qqbuf[quad * 4 + 1][col] = (u16)(q01 >> 16);
            qqbuf[quad * 4 + 2][col] = (u16)q23;
            qqbuf[quad * 4 + 3][col] = (u16)(q23 >> 16);
        }
#pragma unroll
        for (int i = 0; i < 4; ++i) {
            z6c[i] = agv[i] + sw6[i] + qw6[i];
            ac[i] = an[i];
        }
        bar += 8; wgsync(&sctr, bar);
    }

#pragma unroll
    for (int i = 0; i < 4; ++i) {
        const int row = quad * 4 + i;
        const float v = sigm(kold[i]);
        const int off = (b0 + row) * EDIM + col;
        if (BF) ((u16*)outv)[off] = f2bf(v);
        else    ((float*)outv)[off] = v;
    }
}

// ---------------------------------------------------------------------------
extern "C" void kernel_launch(void* const* d_in, const int* in_sizes, int n_in,
                              void* d_out, int out_size, void* d_ws, size_t ws_size,
                              hipStream_t stream) {
    static const int exp_sizes[27] = {
        128000, 128000, 128000, 128000, 128000,
        128000, 128000, 128000, 128000,
        16384000,
        128128, 13056, 13056, 256, 128,
        65536, 128, 16384, 128, 16384, 128,
        32768, 128, 32768, 128, 65536, 128
    };
    bool sizes_ok = (n_in == 27) && (out_size == 32768);
    if (sizes_ok)
        for (int i = 0; i < 27; ++i)
            if (in_sizes[i] != exp_sizes[i]) { sizes_ok = false; break; }
    if (!sizes_ok) {
        dimkt_sentinel<<<dim3(128), dim3(256), 0, stream>>>((u16*)d_out, (u16)0xC080); // -4.0
        return;
    }
    const size_t WS_NEED = 724480;                       // f32 tables
    const size_t WS_FB   = WS_NEED + 32768000u;          // + INP16 (proven tier, R6)
    if (ws_size < WS_FB) {
        dimkt_sentinel<<<dim3(128), dim3(256), 0, stream>>>((u16*)d_out, (u16)0x4110); // 9.0
        return;
    }
    const size_t WS_PK   = WS_NEED + 65536000u;          // INPZ6T u32
    const size_t WS_FAST = WS_PK + 32768000u + 131072u;  // + qe16 + W1bf
    const int pk   = (ws_size >= WS_PK) ? 1 : 0;
    const int fast = (ws_size >= WS_FAST) ? 1 : 0;

    const int* c   = (const int*)d_in[1];
    const int* sd  = (const int*)d_in[2];
    const int* qd  = (const int*)d_in[3];
    const int* a   = (const int*)d_in[4];
    const void* q_emb = d_in[9];
    const void* c_tab = d_in[10];
    const void* sd_tab = d_in[11];
    const void* qd_tab = d_in[12];
    const void* a_tab = d_in[13];
    const void* knowledge = d_in[14];
    const void* W1 = d_in[15]; const void* b1 = d_in[16];
    const void* W2 = d_in[17]; const void* b2 = d_in[18];
    const void* W3 = d_in[19]; const void* b3 = d_in[20];
    const void* W4 = d_in[21]; const void* b4 = d_in[22];
    const void* W5 = d_in[23]; const void* b5 = d_in[24];
    const void* W6 = d_in[25]; const void* b6 = d_in[26];

    float* wsf = (float*)d_ws;
    float* cW1p = wsf;                 // 1001*128
    float* sdQ  = wsf + 128128;        // 102*256
    float* qdQ  = wsf + 154240;        // 102*256
    float* aW6p = wsf + 180352;        // 2*128 (+b6)
    float* c4t  = wsf + 180608;        // 2*128 (+b4)
    float* c5t  = wsf + 180864;        // 2*128 (+b5)
    u16* INP16  = (u16*)((char*)d_ws + WS_NEED);   // FB tier payload
    u32* INPZ6T = (u32*)((char*)d_ws + WS_NEED);   // PK tier payload (same slot)
    u16* qe16   = (u16*)((char*)d_ws + WS_PK);
    u16* W1b    = (u16*)((char*)d_ws + WS_PK + 32768000u);

    dimkt_tabs<<<dim3(1415), dim3(128), 0, stream>>>(
        q_emb, c_tab, sd_tab, qd_tab, a_tab, W1, W4, W5, W6, b4, b5, b6,
        cW1p, sdQ, qdQ, aW6p, c4t, c5t);

    if (fast) {
        dimkt_qe16<<<dim3(8000), dim3(256), 0, stream>>>((const float*)q_emb, qe16);
        dimkt_w1bf<<<dim3(256), dim3(256), 0, stream>>>(W1, q_emb, W1b);
    }

    dimkt_inp<<<dim3(500, 16), dim3(64), 0, stream>>>(
        q_emb, qe16, W1b, fast, W1, b1, c, sd, qd, a,
        cW1p, sdQ, qdQ, aW6p, INP16, INPZ6T, pk);

    if (pk) {
        dimkt_scan_pk<true><<<dim3(16), dim3(512), 0, stream>>>(
            q_emb, INPZ6T, a, W2, b2, W3, b3, W4, W5, W6, knowledge, c4t, c5t, d_out);
        dimkt_scan_pk<false><<<dim3(16), dim3(512), 0, stream>>>(
            q_emb, INPZ6T, a, W2, b2, W3, b3, W4, W5, W6, knowledge, c4t, c5t, d_out);
    } else {
        constexpr int DYN_BYTES = 2 * 102 * 130 * 2 + 2 * 132 * 4;   // 54,096 B
        hipFuncSetAttribute(reinterpret_cast<const void*>(&dimkt_scan_fb<true>),
                            hipFuncAttributeMaxDynamicSharedMemorySize, DYN_BYTES);
        hipFuncSetAttribute(reinterpret_cast<const void*>(&dimkt_scan_fb<false>),
                            hipFuncAttributeMaxDynamicSharedMemorySize, DYN_BYTES);
        dimkt_scan_fb<true><<<dim3(16), dim3(512), DYN_BYTES, stream>>>(
            q_emb, INP16, c, sd, qd, a, W2, b2, W3, b3, W4, W5, W6, knowledge,
            sdQ, qdQ, aW6p, c4t, c5t, d_out);
        dimkt_scan_fb<false><<<dim3(16), dim3(512), DYN_BYTES, stream>>>(
            q_emb, INP16, c, sd, qd, a, W2, b2, W3, b3, W4, W5, W6, knowledge,
            sdQ, qdQ, aW6p, c4t, c5t, d_out);
    }
}

// Round 8
// 950.697 us; speedup vs baseline: 2.1351x; 1.0501x over previous
//
#include <hip/hip_runtime.h>

typedef unsigned short u16;
typedef unsigned int u32;
typedef short bf16x8 __attribute__((ext_vector_type(8)));
typedef float f32x4 __attribute__((ext_vector_type(4)));

#define S_LEN 500
#define NB 256
#define EDIM 128

__device__ __forceinline__ float bf2f(u16 u) { return __uint_as_float(((u32)u) << 16); }
__device__ __forceinline__ u16 f2bf(float f) {
    u32 x = __float_as_uint(f);
    x += 0x7FFFu + ((x >> 16) & 1u);   // round-to-nearest-even
    return (u16)(x >> 16);
}
// HW packed f32->bf16 (RNE, matches f2bf): 1 inst for 2 values. lo->bits[15:0].
__device__ __forceinline__ u32 cvtpk(float lo, float hi) {
    u32 r;
    asm("v_cvt_pk_bf16_f32 %0, %1, %2" : "=v"(r) : "v"(lo), "v"(hi));
    return r;
}
__device__ __forceinline__ float fexp(float x) { return __builtin_amdgcn_exp2f(x * 1.44269504089f); }
__device__ __forceinline__ float frcp(float x) { return __builtin_amdgcn_rcpf(x); }
__device__ __forceinline__ float sigm(float x) { return frcp(1.0f + fexp(-x)); }
__device__ __forceinline__ float tanh_(float x) { return 1.0f - 2.0f * frcp(1.0f + fexp(2.0f * x)); }
__device__ __forceinline__ int iclamp(int v, int hi) { return v < 0 ? 0 : (v > hi ? hi : v); }

// ---------------------------------------------------------------------------
// R1-proven workgroup sync: lane-0 atomicAdd on an LDS counter + broadcast
// poll. Measured FASTER than raw s_barrier on this kernel (1490 vs 1878 us)
// -- staggered release naturally de-synchronizes the 2 waves/SIMD bursts.
// ---------------------------------------------------------------------------
__device__ __forceinline__ void wgsync(volatile int* c, int target) {
    __asm__ volatile("s_waitcnt lgkmcnt(0)" ::: "memory");  // prior LDS writes done
    if ((threadIdx.x & 63) == 0) atomicAdd((int*)c, 1);
    while (*c < target) {}
    __asm__ volatile("" ::: "memory");
}

// ---------------------------------------------------------------------------
// Runtime float-dtype detection from q_embedding bit patterns (wave-uniform).
// ---------------------------------------------------------------------------
__device__ __forceinline__ bool detect_bf16(const void* q) {
    const u16* w = (const u16*)q;
    int plaus = 0;
#pragma unroll 1
    for (int i = 0; i < 64; ++i) {
        const u16 v = w[2 * i];
        const int e = (v >> 7) & 0xFF;
        plaus += (v == 0 || (e >= 100 && e <= 130)) ? 1 : 0;
    }
    return plaus >= 48;
}
__device__ __forceinline__ float ldF(const void* p, int i, bool bf) {
    return bf ? bf2f(((const u16*)p)[i]) : ((const float*)p)[i];
}
template <bool BF>
__device__ __forceinline__ bf16x8 ldfragT(const void* p, int i) {
    if (BF) return *(const bf16x8*)((const u16*)p + i);
    const float* f = (const float*)p + i;
    bf16x8 r;
#pragma unroll
    for (int e = 0; e < 8; ++e) r[e] = (short)f2bf(f[e]);
    return r;
}
// runtime-dtype fragment loader (wave-uniform bf flag)
__device__ __forceinline__ bf16x8 ldfragR(const void* p, int i, bool bf) {
    if (bf) return *(const bf16x8*)((const u16*)p + i);
    const float* f = (const float*)p + i;
    bf16x8 r;
#pragma unroll
    for (int e = 0; e < 8; ++e) r[e] = (short)f2bf(f[e]);
    return r;
}

__global__ void dimkt_sentinel(u16* __restrict__ out, u16 val) {
    out[blockIdx.x * 256 + threadIdx.x] = val;
}

// ---------------------------------------------------------------------------
// K-conv: one-time q_emb f32 -> bf16 (guarded: no-op when input is bf16).
// ---------------------------------------------------------------------------
__global__ void dimkt_qe16(const float* __restrict__ qf, u16* __restrict__ qe16) {
    if (detect_bf16(qf)) return;
    const int i = (blockIdx.x * 256 + threadIdx.x) * 8;
    const float4 a = *(const float4*)(qf + i);
    const float4 b = *(const float4*)(qf + i + 4);
    ushort4 lo, hi;
    lo.x = f2bf(a.x); lo.y = f2bf(a.y); lo.z = f2bf(a.z); lo.w = f2bf(a.w);
    hi.x = f2bf(b.x); hi.y = f2bf(b.y); hi.z = f2bf(b.z); hi.w = f2bf(b.w);
    *(ushort4*)(qe16 + i) = lo;
    *(ushort4*)(qe16 + i + 4) = hi;
}

// K-conv: W1 -> bf16 (or copy if already bf16). 128*512 = 65,536 elems.
__global__ void dimkt_w1bf(const void* __restrict__ W1, const void* __restrict__ qref,
                           u16* __restrict__ W1b) {
    const bool bf = detect_bf16(qref);
    const int i = blockIdx.x * 256 + threadIdx.x;
    W1b[i] = bf ? ((const u16*)W1)[i] : f2bf(((const float*)W1)[i]);
}

// ---------------------------------------------------------------------------
// K0: tiny gather-table precompute. Layout (per-col scalar):
//   cW1p[cx*128 + col] ; sdQ/qdQ[x*256 + col*2 + {0:W1,1:W6}]
//   aW6p[ax*128 + col] (+b6) ; c4t/c5t[ax*128 + col] (+b4/+b5)
// ---------------------------------------------------------------------------
__global__ void dimkt_tabs(const void* __restrict__ q_emb,
                           const void* __restrict__ c_tab, const void* __restrict__ sd_tab,
                           const void* __restrict__ qd_tab, const void* __restrict__ a_tab,
                           const void* __restrict__ W1, const void* __restrict__ W4,
                           const void* __restrict__ W5, const void* __restrict__ W6,
                           const void* __restrict__ b4, const void* __restrict__ b5,
                           const void* __restrict__ b6,
                           float* __restrict__ cW1p, float* __restrict__ sdQ,
                           float* __restrict__ qdQ, float* __restrict__ aW6p,
                           float* __restrict__ c4t, float* __restrict__ c5t) {
    const bool bf = detect_bf16(q_emb);
    __shared__ float src[128];
    const int r = blockIdx.x, n = threadIdx.x;
    const void* srcp; const void* W; const void* bias = nullptr;
    int soff, koff, ld, oidx; float* outp; bool mask;
    if (r < 1001)      { srcp = c_tab;  soff = r * 128;               W = W1; koff = 128; ld = 512; outp = cW1p; oidx = r * 128 + n;           mask = (r == 0); }
    else if (r < 1103) { int rr = r - 1001; srcp = sd_tab; soff = rr * 128; W = W1; koff = 256; ld = 512; outp = sdQ;  oidx = rr * 256 + n * 2;     mask = (rr == 0); }
    else if (r < 1205) { int rr = r - 1103; srcp = qd_tab; soff = rr * 128; W = W1; koff = 384; ld = 512; outp = qdQ;  oidx = rr * 256 + n * 2;     mask = (rr == 0); }
    else if (r < 1307) { int rr = r - 1205; srcp = sd_tab; soff = rr * 128; W = W6; koff = 256; ld = 512; outp = sdQ;  oidx = rr * 256 + n * 2 + 1; mask = (rr == 0); }
    else if (r < 1409) { int rr = r - 1307; srcp = qd_tab; soff = rr * 128; W = W6; koff = 384; ld = 512; outp = qdQ;  oidx = rr * 256 + n * 2 + 1; mask = (rr == 0); }
    else if (r < 1411) { int rr = r - 1409; srcp = a_tab;  soff = rr * 128; W = W6; koff = 128; ld = 512; outp = aW6p; oidx = rr * 128 + n;         bias = b6; mask = false; }
    else if (r < 1413) { int rr = r - 1411; srcp = a_tab;  soff = rr * 128; W = W4; koff = 128; ld = 256; outp = c4t;  oidx = rr * 128 + n;         bias = b4; mask = false; }
    else               { int rr = r - 1413; srcp = a_tab;  soff = rr * 128; W = W5; koff = 128; ld = 256; outp = c5t;  oidx = rr * 128 + n;         bias = b5; mask = false; }
    src[n] = ldF(srcp, soff + n, bf);
    __syncthreads();
    float acc = 0.f;
    if (!mask) {
        if (bf) {
            const u16* Wp = (const u16*)W + n * ld + koff;
#pragma unroll 4
            for (int k = 0; k < 128; k += 8) {
                const ushort4 wa = *(const ushort4*)(Wp + k);
                const ushort4 wb = *(const ushort4*)(Wp + k + 4);
                acc += src[k] * bf2f(wa.x) + src[k + 1] * bf2f(wa.y)
                     + src[k + 2] * bf2f(wa.z) + src[k + 3] * bf2f(wa.w)
                     + src[k + 4] * bf2f(wb.x) + src[k + 5] * bf2f(wb.y)
                     + src[k + 6] * bf2f(wb.z) + src[k + 7] * bf2f(wb.w);
            }
        } else {
            const float* Wp = (const float*)W + n * ld + koff;
#pragma unroll 4
            for (int k = 0; k < 128; k += 4) {
                const float4 w4 = *(const float4*)(Wp + k);
                acc += src[k] * w4.x + src[k + 1] * w4.y + src[k + 2] * w4.z + src[k + 3] * w4.w;
            }
        }
        if (bias) acc += ldF(bias, n, bf);
    }
    outp[oidx] = acc;
}

// ---------------------------------------------------------------------------
// K1: INP(+Z6) precompute. pk=1: store u32 {inp(bf16 lo), z6(bf16 hi)} in
// TRANSPOSED layout INPZ6T[(t*128+col)*256 + row] -> the scan fetches its 4
// rows with ONE dwordx4 per step. pk=0: R6-style bf16 INP16 row-major.
// fastpath=1: ae/W1 fragments from pre-converted bf16 (vector loads).
// ---------------------------------------------------------------------------
__global__ void dimkt_inp(const void* __restrict__ q_emb, const u16* __restrict__ qe16,
                          const u16* __restrict__ W1b, const int fastpath,
                          const void* __restrict__ W1, const void* __restrict__ b1,
                          const int* __restrict__ cI, const int* __restrict__ sI,
                          const int* __restrict__ qI, const int* __restrict__ aI,
                          const float* __restrict__ cW1p, const float* __restrict__ sdQ,
                          const float* __restrict__ qdQ, const float* __restrict__ aW6p,
                          u16* __restrict__ INP16, u32* __restrict__ INPZ6T, const int pk) {
    const bool bf = detect_bf16(q_emb);
    const int t = blockIdx.x, rc = blockIdx.y;
    const int lane = threadIdx.x, quad = lane >> 4, l15 = lane & 15;
    const bool fA = bf || (fastpath != 0);
    const u16* aes = bf ? (const u16*)q_emb : qe16;
    bf16x8 ae[4];
#pragma unroll
    for (int ks = 0; ks < 4; ++ks) {
        const int off = ((rc * 16 + l15) * S_LEN + t) * EDIM + ks * 32 + quad * 8;
        ae[ks] = fA ? *(const bf16x8*)(aes + off) : ldfragR(q_emb, off, false);
    }
    int cx[4], sx[4], qx[4], ax[4];
#pragma unroll
    for (int i = 0; i < 4; ++i) {
        const int off = (rc * 16 + quad * 4 + i) * S_LEN + t;
        cx[i] = iclamp(cI[off], 1000);
        sx[i] = iclamp(sI[off], 101);
        qx[i] = iclamp(qI[off], 101);
        ax[i] = iclamp(aI[off], 1);
    }
#pragma unroll 1
    for (int ct = 0; ct < 8; ++ct) {
        const int colc = ct * 16 + l15;
        bf16x8 w[4];
#pragma unroll
        for (int ks = 0; ks < 4; ++ks) {
            const int woff = colc * 512 + ks * 32 + quad * 8;
            w[ks] = fastpath ? *(const bf16x8*)(W1b + woff) : ldfragR(W1, woff, bf);
        }
        const float b1c = ldF(b1, colc, bf);
        f32x4 acc; float z6v[4];
#pragma unroll
        for (int i = 0; i < 4; ++i) {
            const float2 sgp = *(const float2*)(sdQ + sx[i] * 256 + colc * 2);
            const float2 qgp = *(const float2*)(qdQ + qx[i] * 256 + colc * 2);
            acc[i] = b1c + cW1p[cx[i] * 128 + colc] + sgp.x + qgp.x;
            z6v[i] = pk ? (aW6p[ax[i] * 128 + colc] + sgp.y + qgp.y) : 0.f;
        }
#pragma unroll
        for (int ks = 0; ks < 4; ++ks)
            acc = __builtin_amdgcn_mfma_f32_16x16x32_bf16(ae[ks], w[ks], acc, 0, 0, 0);
        if (pk) {
            uint4 st;
            st.x = cvtpk(acc[0], z6v[0]); st.y = cvtpk(acc[1], z6v[1]);
            st.z = cvtpk(acc[2], z6v[2]); st.w = cvtpk(acc[3], z6v[3]);
            *(uint4*)(INPZ6T + ((size_t)t * 128 + colc) * 256 + rc * 16 + quad * 4) = st;
        } else {
#pragma unroll
            for (int i = 0; i < 4; ++i)
                INP16[((size_t)t * 256 + rc * 16 + quad * 4 + i) * 128 + colc] = f2bf(acc[i]);
        }
    }
}

// ---------------------------------------------------------------------------
// K2-PK: fused 500-step scan, packed-input form. 16 WGs x 512 threads.
// R8 changes (all bit-exact or f32-reassociation-only):
//  - XOR-swizzled k/qq/sd buffers: element (r,c) at u16-index c^((r>>2)<<3).
//    Write banks partition per quad (4-way -> 2-way = free); fragment reads
//    stay at the 8-access/bank saturation minimum. Zero extra instructions.
//  - Last iteration peeled -> main loop is affine -> pz/aI become simple
//    pointer increments (kills per-step v_mad_u64 chains + cndmasks).
//  - Un-split MFMA chains (4-deep, bias-initialized): -24 VALU, -12 VGPR;
//    3-way (B) / 2-way (C) inter-chain ILP still hides MFMA latency.
// ---------------------------------------------------------------------------
template <bool BF>
__global__ __launch_bounds__(512, 2) void dimkt_scan_pk(
    const void* __restrict__ q_emb, const u32* __restrict__ INPZ6T,
    const int* __restrict__ aI,
    const void* __restrict__ W2, const void* __restrict__ b2,
    const void* __restrict__ W3, const void* __restrict__ b3,
    const void* __restrict__ W4, const void* __restrict__ W5,
    const void* __restrict__ W6, const void* __restrict__ knowledge,
    const float* __restrict__ c4t, const float* __restrict__ c5t,
    void* __restrict__ outv) {
    if (detect_bf16(q_emb) != BF) return;   // wrong specialization: uniform exit
    __shared__ __align__(16) u16 kbuf[16][136];
    __shared__ __align__(16) u16 qqbuf[16][136];
    __shared__ __align__(16) u16 sdbuf[16][136];
    __shared__ int sctr;

    const int tid = threadIdx.x;
    const int wv = tid >> 6, lane = tid & 63;
    const int quad = lane >> 4, l15 = lane & 15;
    const int b0 = blockIdx.x * 16;
    const int col = wv * 16 + l15;
    const int quadX = quad ^ (l15 >> 2);   // read-side swizzled chunk index
    const int wcolX = col ^ (quad << 3);   // write-side swizzled column

    // ---- stationary weight fragments (registers, 500-step resident) ----
    bf16x8 fW2[4], fW3[4], fW4[4], fW5[4], fW6[4];
#pragma unroll
    for (int ks = 0; ks < 4; ++ks) {
        const int ko = ks * 32 + quad * 8;
        fW2[ks] = ldfragT<BF>(W2, col * 128 + ko);
        fW3[ks] = ldfragT<BF>(W3, col * 128 + ko);
        fW4[ks] = ldfragT<BF>(W4, col * 256 + ko);   // W4[:, :128]
        fW5[ks] = ldfragT<BF>(W5, col * 256 + ko);   // W5[:, :128]
        fW6[ks] = ldfragT<BF>(W6, col * 512 + ko);   // W6[:, :128]
    }
    const float b2v = ldF(b2, col, BF);
    const float b3v = ldF(b3, col, BF);
    const float c4_0 = c4t[col], c4_1 = c4t[128 + col];
    const float c5_0 = c5t[col], c5_1 = c5t[128 + col];

    const u32* pzBase = INPZ6T + (size_t)col * 256 + b0 + quad * 4;
    const int* aBase = aI + (b0 + quad * 4) * S_LEN;

    // ---- t=0 init ----
    float kold[4], z6c[4], g[4];
    int ac[4];
    {
        const float k0 = ldF(knowledge, col, BF);
        const u16 k0b = f2bf(k0);
        const uint4 pz0 = *(const uint4*)pzBase;
        const u32 pzv[4] = {pz0.x, pz0.y, pz0.z, pz0.w};
        if (tid == 0) sctr = 0;
#pragma unroll
        for (int i = 0; i < 4; ++i) {
            ac[i] = iclamp(aBase[i * S_LEN], 1);
            z6c[i] = __uint_as_float(pzv[i] & 0xFFFF0000u);
            const float inp0 = __uint_as_float(pzv[i] << 16);
            kold[i] = k0;
            kbuf[quad * 4 + i][wcolX] = k0b;
            qqbuf[quad * 4 + i][wcolX] = f2bf(k0 - inp0);
        }
    }
    __syncthreads();   // one real barrier pre-loop

    const u32* pzP = pzBase + 32768;   // {inp,z6} stream, t+1
    const int* aP = aBase + 1;         // a stream, t+1
    int bar = 0;
#pragma unroll 1
    for (int t = 0; t < S_LEN - 1; ++t) {
        // ---- prefetch t+1: a-bits + packed {inp,z6} (pointer-increment) ----
        int an[4];
#pragma unroll
        for (int i = 0; i < 4; ++i) an[i] = iclamp(aP[i * S_LEN], 1);
        const uint4 pzN = *(const uint4*)pzP;
        aP += 1; pzP += 32768;

        // ---- phase B: Y2/Y3 on qq, Y6 on k; sdft -> LDS ----
        bf16x8 aq[4], ak[4];
#pragma unroll
        for (int ks = 0; ks < 4; ++ks) {
            aq[ks] = *(const bf16x8*)&qqbuf[l15][ks * 32 + quadX * 8];
            ak[ks] = *(const bf16x8*)&kbuf[l15][ks * 32 + quadX * 8];
        }
        f32x4 Y2 = (f32x4){b2v, b2v, b2v, b2v};
        f32x4 Y3 = (f32x4){b3v, b3v, b3v, b3v};
        f32x4 Y6 = (f32x4){z6c[0], z6c[1], z6c[2], z6c[3]};
#pragma unroll
        for (int ks = 0; ks < 4; ++ks) {
            Y2 = __builtin_amdgcn_mfma_f32_16x16x32_bf16(aq[ks], fW2[ks], Y2, 0, 0, 0);
            Y3 = __builtin_amdgcn_mfma_f32_16x16x32_bf16(aq[ks], fW3[ks], Y3, 0, 0, 0);
            Y6 = __builtin_amdgcn_mfma_f32_16x16x32_bf16(ak[ks], fW6[ks], Y6, 0, 0, 0);
        }
        float sdv[4];
#pragma unroll
        for (int i = 0; i < 4; ++i) sdv[i] = sigm(Y2[i]) * tanh_(Y3[i]);
        {
            const u32 s01 = cvtpk(sdv[0], sdv[1]), s23 = cvtpk(sdv[2], sdv[3]);
            sdbuf[quad * 4 + 0][wcolX] = (u16)s01;
            sdbuf[quad * 4 + 1][wcolX] = (u16)(s01 >> 16);
            sdbuf[quad * 4 + 2][wcolX] = (u16)s23;
            sdbuf[quad * 4 + 3][wcolX] = (u16)(s23 >> 16);
        }
        bar += 8; wgsync(&sctr, bar);

        // ---- phase C: Y4/Y5 on sdft; g; k update; write k/qq for t+1 ----
        bf16x8 as[4];
#pragma unroll
        for (int ks = 0; ks < 4; ++ks)
            as[ks] = *(const bf16x8*)&sdbuf[l15][ks * 32 + quadX * 8];
#pragma unroll
        for (int i = 0; i < 4; ++i) g[i] = sigm(Y6[i]);
        f32x4 Y4 = (f32x4){ac[0] ? c4_1 : c4_0, ac[1] ? c4_1 : c4_0,
                           ac[2] ? c4_1 : c4_0, ac[3] ? c4_1 : c4_0};
        f32x4 Y5 = (f32x4){ac[0] ? c5_1 : c5_0, ac[1] ? c5_1 : c5_0,
                           ac[2] ? c5_1 : c5_0, ac[3] ? c5_1 : c5_0};
#pragma unroll
        for (int ks = 0; ks < 4; ++ks) {
            Y4 = __builtin_amdgcn_mfma_f32_16x16x32_bf16(as[ks], fW4[ks], Y4, 0, 0, 0);
            Y5 = __builtin_amdgcn_mfma_f32_16x16x32_bf16(as[ks], fW5[ks], Y5, 0, 0, 0);
        }
        const u32 pzv[4] = {pzN.x, pzN.y, pzN.z, pzN.w};
        float knA[4], qqA[4];
#pragma unroll
        for (int i = 0; i < 4; ++i) {
            const float pk = sigm(Y4[i]) * tanh_(Y5[i]);
            const float kn = g[i] * kold[i] + (1.0f - g[i]) * pk;
            kold[i] = kn; knA[i] = kn;
            qqA[i] = kn - __uint_as_float(pzv[i] << 16);    // qq_{t+1} = k - inp_{t+1}
        }
        {
            const u32 k01 = cvtpk(knA[0], knA[1]), k23 = cvtpk(knA[2], knA[3]);
            const u32 q01 = cvtpk(qqA[0], qqA[1]), q23 = cvtpk(qqA[2], qqA[3]);
            kbuf[quad * 4 + 0][wcolX] = (u16)k01;
            kbuf[quad * 4 + 1][wcolX] = (u16)(k01 >> 16);
            kbuf[quad * 4 + 2][wcolX] = (u16)k23;
            kbuf[quad * 4 + 3][wcolX] = (u16)(k23 >> 16);
            qqbuf[quad * 4 + 0][wcolX] = (u16)q01;
            qqbuf[quad * 4 + 1][wcolX] = (u16)(q01 >> 16);
            qqbuf[quad * 4 + 2][wcolX] = (u16)q23;
            qqbuf[quad * 4 + 3][wcolX] = (u16)(q23 >> 16);
        }
        // ---- rotate: z6/ac for t+1 (straight from packed load) ----
#pragma unroll
        for (int i = 0; i < 4; ++i) {
            z6c[i] = __uint_as_float(pzv[i] & 0xFFFF0000u);
            ac[i] = an[i];
        }
        bar += 8; wgsync(&sctr, bar);
    }

    // ---- peeled final step (t = S_LEN-1): no prefetch, no next-state
    //      writes, no trailing sync (epilogue is thread-local) ----
    {
        bf16x8 aq[4], ak[4];
#pragma unroll
        for (int ks = 0; ks < 4; ++ks) {
            aq[ks] = *(const bf16x8*)&qqbuf[l15][ks * 32 + quadX * 8];
            ak[ks] = *(const bf16x8*)&kbuf[l15][ks * 32 + quadX * 8];
        }
        f32x4 Y2 = (f32x4){b2v, b2v, b2v, b2v};
        f32x4 Y3 = (f32x4){b3v, b3v, b3v, b3v};
        f32x4 Y6 = (f32x4){z6c[0], z6c[1], z6c[2], z6c[3]};
#pragma unroll
        for (int ks = 0; ks < 4; ++ks) {
            Y2 = __builtin_amdgcn_mfma_f32_16x16x32_bf16(aq[ks], fW2[ks], Y2, 0, 0, 0);
            Y3 = __builtin_amdgcn_mfma_f32_16x16x32_bf16(aq[ks], fW3[ks], Y3, 0, 0, 0);
            Y6 = __builtin_amdgcn_mfma_f32_16x16x32_bf16(ak[ks], fW6[ks], Y6, 0, 0, 0);
        }
        float sdv[4];
#pragma unroll
        for (int i = 0; i < 4; ++i) sdv[i] = sigm(Y2[i]) * tanh_(Y3[i]);
        {
            const u32 s01 = cvtpk(sdv[0], sdv[1]), s23 = cvtpk(sdv[2], sdv[3]);
            sdbuf[quad * 4 + 0][wcolX] = (u16)s01;
            sdbuf[quad * 4 + 1][wcolX] = (u16)(s01 >> 16);
            sdbuf[quad * 4 + 2][wcolX] = (u16)s23;
            sdbuf[quad * 4 + 3][wcolX] = (u16)(s23 >> 16);
        }
        bar += 8; wgsync(&sctr, bar);

        bf16x8 as[4];
#pragma unroll
        for (int ks = 0; ks < 4; ++ks)
            as[ks] = *(const bf16x8*)&sdbuf[l15][ks * 32 + quadX * 8];
#pragma unroll
        for (int i = 0; i < 4; ++i) g[i] = sigm(Y6[i]);
        f32x4 Y4 = (f32x4){ac[0] ? c4_1 : c4_0, ac[1] ? c4_1 : c4_0,
                           ac[2] ? c4_1 : c4_0, ac[3] ? c4_1 : c4_0};
        f32x4 Y5 = (f32x4){ac[0] ? c5_1 : c5_0, ac[1] ? c5_1 : c5_0,
                           ac[2] ? c5_1 : c5_0, ac[3] ? c5_1 : c5_0};
#pragma unroll
        for (int ks = 0; ks < 4; ++ks) {
            Y4 = __builtin_amdgcn_mfma_f32_16x16x32_bf16(as[ks], fW4[ks], Y4, 0, 0, 0);
            Y5 = __builtin_amdgcn_mfma_f32_16x16x32_bf16(as[ks], fW5[ks], Y5, 0, 0, 0);
        }
#pragma unroll
        for (int i = 0; i < 4; ++i) {
            const float pk = sigm(Y4[i]) * tanh_(Y5[i]);
            kold[i] = g[i] * kold[i] + (1.0f - g[i]) * pk;
        }
    }

    // ---- epilogue: out = sigmoid(k_final), [B][E], dtype matches input ----
#pragma unroll
    for (int i = 0; i < 4; ++i) {
        const int row = quad * 4 + i;
        const float v = sigm(kold[i]);
        const int off = (b0 + row) * EDIM + col;
        if (BF) ((u16*)outv)[off] = f2bf(v);
        else    ((float*)outv)[off] = v;
    }
}

// ---------------------------------------------------------------------------
// K2-FB: R6 scan, verbatim (fallback when ws can't hold INPZ6T).
// ---------------------------------------------------------------------------
template <bool BF>
__global__ __launch_bounds__(512, 2) void dimkt_scan_fb(
    const void* __restrict__ q_emb, const u16* __restrict__ INP16,
    const int* __restrict__ cI, const int* __restrict__ sI,
    const int* __restrict__ qI, const int* __restrict__ aI,
    const void* __restrict__ W2, const void* __restrict__ b2,
    const void* __restrict__ W3, const void* __restrict__ b3,
    const void* __restrict__ W4, const void* __restrict__ W5,
    const void* __restrict__ W6, const void* __restrict__ knowledge,
    const float* __restrict__ sdQ, const float* __restrict__ qdQ,
    const float* __restrict__ aW6p, const float* __restrict__ c4t,
    const float* __restrict__ c5t, void* __restrict__ outv) {
    if (detect_bf16(q_emb) != BF) return;
    __shared__ __align__(16) u16 kbuf[16][136];
    __shared__ __align__(16) u16 qqbuf[16][136];
    __shared__ __align__(16) u16 sdbuf[16][136];
    __shared__ u32 idxL[16][S_LEN];
    __shared__ int sctr;
    extern __shared__ __align__(16) u16 dynLDS[];
    u16* sdT = dynLDS;
    u16* qdT = dynLDS + 102 * 130;
    float* aW6L = (float*)(dynLDS + 2 * 102 * 130);

    const int tid = threadIdx.x;
    const int wv = tid >> 6, lane = tid & 63;
    const int quad = lane >> 4, l15 = lane & 15;
    const int b0 = blockIdx.x * 16;
    const int col = wv * 16 + l15;
    const int col2 = col * 2;

    bf16x8 fW2[4], fW3[4], fW4[4], fW5[4], fW6[4];
#pragma unroll
    for (int ks = 0; ks < 4; ++ks) {
        const int ko = ks * 32 + quad * 8;
        fW2[ks] = ldfragT<BF>(W2, col * 128 + ko);
        fW3[ks] = ldfragT<BF>(W3, col * 128 + ko);
        fW4[ks] = ldfragT<BF>(W4, col * 256 + ko);
        fW5[ks] = ldfragT<BF>(W5, col * 256 + ko);
        fW6[ks] = ldfragT<BF>(W6, col * 512 + ko);
    }
    const float b2v = ldF(b2, col, BF);
    const float b3v = ldF(b3, col, BF);
    const float c4_0 = c4t[col], c4_1 = c4t[128 + col];
    const float c5_0 = c5t[col], c5_1 = c5t[128 + col];

#pragma unroll 1
    for (int r = 0; r < 16; ++r)
#pragma unroll 1
        for (int t = tid; t < S_LEN; t += 512) {
            const int off = (b0 + r) * S_LEN + t;
            idxL[r][t] = (u32)iclamp(cI[off], 1000)
                       | ((u32)iclamp(sI[off], 101) << 10)
                       | ((u32)iclamp(qI[off], 101) << 17)
                       | ((u32)iclamp(aI[off], 1) << 24);
        }
#pragma unroll 1
    for (int v = tid; v < 102 * 128; v += 512) {
        const int sx = v >> 7, cc = v & 127;
        sdT[sx * 130 + cc] = f2bf(sdQ[sx * 256 + cc * 2 + 1]);
        qdT[sx * 130 + cc] = f2bf(qdQ[sx * 256 + cc * 2 + 1]);
    }
    if (tid < 256) {
        const int rr = tid >> 7, cc = tid & 127;
        aW6L[rr * 132 + cc] = aW6p[rr * 128 + cc];
    }
    if (tid == 0) sctr = 0;
    __syncthreads();

    float kold[4], z6c[4], g[4];
    int ac[4];
    {
        const float k0 = ldF(knowledge, col, BF);
        const u16 k0b = f2bf(k0);
#pragma unroll
        for (int i = 0; i < 4; ++i) {
            const u32 p = idxL[quad * 4 + i][0];
            const int sx = (p >> 10) & 127, qx = (p >> 17) & 127, ax = (p >> 24) & 1;
            ac[i] = ax;
            const float2 sgp = *(const float2*)(sdQ + sx * 256 + col2);
            const float2 qgp = *(const float2*)(qdQ + qx * 256 + col2);
            z6c[i] = aW6p[ax * 128 + col] + sgp.y + qgp.y;
            const float inp0 = bf2f(INP16[(size_t)(b0 + quad * 4 + i) * 128 + col]);
            kold[i] = k0;
            kbuf[quad * 4 + i][col] = k0b;
            qqbuf[quad * 4 + i][col] = f2bf(k0 - inp0);
        }
    }
    u32 pk4[4];
#pragma unroll
    for (int i = 0; i < 4; ++i) pk4[i] = idxL[quad * 4 + i][1];
    __syncthreads();

    int bar = 0;
#pragma unroll 1
    for (int t = 0; t < S_LEN; ++t) {
        const int tf2 = (t + 2 < S_LEN) ? t + 2 : S_LEN - 1;
        const int tp = (t + 1 < S_LEN) ? t + 1 : S_LEN - 1;
        int an[4];
        u16 inpN[4];
        float sw6[4], qw6[4], agv[4];
#pragma unroll
        for (int i = 0; i < 4; ++i) {
            const u32 p = pk4[i];
            const int sx = (p >> 10) & 127, qx = (p >> 17) & 127;
            an[i] = (p >> 24) & 1;
            inpN[i] = INP16[((size_t)tp * 256 + b0 + quad * 4 + i) * 128 + col];
            sw6[i] = bf2f(sdT[sx * 130 + col]);
            qw6[i] = bf2f(qdT[qx * 130 + col]);
            agv[i] = aW6L[an[i] * 132 + col];
        }
#pragma unroll
        for (int i = 0; i < 4; ++i) pk4[i] = idxL[quad * 4 + i][tf2];

        bf16x8 aq[4], ak[4];
#pragma unroll
        for (int ks = 0; ks < 4; ++ks) {
            aq[ks] = *(const bf16x8*)&qqbuf[l15][ks * 32 + quad * 8];
            ak[ks] = *(const bf16x8*)&kbuf[l15][ks * 32 + quad * 8];
        }
        f32x4 Y2a = (f32x4){b2v, b2v, b2v, b2v}, Y2b = (f32x4){0.f, 0.f, 0.f, 0.f};
        f32x4 Y3a = (f32x4){b3v, b3v, b3v, b3v}, Y3b = (f32x4){0.f, 0.f, 0.f, 0.f};
        f32x4 Y6a = (f32x4){z6c[0], z6c[1], z6c[2], z6c[3]}, Y6b = (f32x4){0.f, 0.f, 0.f, 0.f};
        Y2a = __builtin_amdgcn_mfma_f32_16x16x32_bf16(aq[0], fW2[0], Y2a, 0, 0, 0);
        Y3a = __builtin_amdgcn_mfma_f32_16x16x32_bf16(aq[0], fW3[0], Y3a, 0, 0, 0);
        Y6a = __builtin_amdgcn_mfma_f32_16x16x32_bf16(ak[0], fW6[0], Y6a, 0, 0, 0);
        Y2b = __builtin_amdgcn_mfma_f32_16x16x32_bf16(aq[2], fW2[2], Y2b, 0, 0, 0);
        Y3b = __builtin_amdgcn_mfma_f32_16x16x32_bf16(aq[2], fW3[2], Y3b, 0, 0, 0);
        Y6b = __builtin_amdgcn_mfma_f32_16x16x32_bf16(ak[2], fW6[2], Y6b, 0, 0, 0);
        Y2a = __builtin_amdgcn_mfma_f32_16x16x32_bf16(aq[1], fW2[1], Y2a, 0, 0, 0);
        Y3a = __builtin_amdgcn_mfma_f32_16x16x32_bf16(aq[1], fW3[1], Y3a, 0, 0, 0);
        Y6a = __builtin_amdgcn_mfma_f32_16x16x32_bf16(ak[1], fW6[1], Y6a, 0, 0, 0);
        Y2b = __builtin_amdgcn_mfma_f32_16x16x32_bf16(aq[3], fW2[3], Y2b, 0, 0, 0);
        Y3b = __builtin_amdgcn_mfma_f32_16x16x32_bf16(aq[3], fW3[3], Y3b, 0, 0, 0);
        Y6b = __builtin_amdgcn_mfma_f32_16x16x32_bf16(ak[3], fW6[3], Y6b, 0, 0, 0);
        const f32x4 Y2 = Y2a + Y2b, Y3 = Y3a + Y3b, Y6 = Y6a + Y6b;
        float sdv[4];
#pragma unroll
        for (int i = 0; i < 4; ++i) sdv[i] = sigm(Y2[i]) * tanh_(Y3[i]);
        {
            const u32 s01 = cvtpk(sdv[0], sdv[1]), s23 = cvtpk(sdv[2], sdv[3]);
            sdbuf[quad * 4 + 0][col] = (u16)s01;
            sdbuf[quad * 4 + 1][col] = (u16)(s01 >> 16);
            sdbuf[quad * 4 + 2][col] = (u16)s23;
            sdbuf[quad * 4 + 3][col] = (u16)(s23 >> 16);
        }
        bar += 8; wgsync(&sctr, bar);

        bf16x8 as[4];
#pragma unroll
        for (int ks = 0; ks < 4; ++ks)
            as[ks] = *(const bf16x8*)&sdbuf[l15][ks * 32 + quad * 8];
#pragma unroll
        for (int i = 0; i < 4; ++i) g[i] = sigm(Y6[i]);
        f32x4 Y4a = (f32x4){ac[0] ? c4_1 : c4_0, ac[1] ? c4_1 : c4_0,
                            ac[2] ? c4_1 : c4_0, ac[3] ? c4_1 : c4_0};
        f32x4 Y5a = (f32x4){ac[0] ? c5_1 : c5_0, ac[1] ? c5_1 : c5_0,
                            ac[2] ? c5_1 : c5_0, ac[3] ? c5_1 : c5_0};
        f32x4 Y4b = (f32x4){0.f, 0.f, 0.f, 0.f}, Y5b = (f32x4){0.f, 0.f, 0.f, 0.f};
        Y4a = __builtin_amdgcn_mfma_f32_16x16x32_bf16(as[0], fW4[0], Y4a, 0, 0, 0);
        Y5a = __builtin_amdgcn_mfma_f32_16x16x32_bf16(as[0], fW5[0], Y5a, 0, 0, 0);
        Y4b = __builtin_amdgcn_mfma_f32_16x16x32_bf16(as[2], fW4[2], Y4b, 0, 0, 0);
        Y5b = __builtin_amdgcn_mfma_f32_16x16x32_bf16(as[2], fW5[2], Y5b, 0, 0, 0);
        Y4a = __builtin_amdgcn_mfma_f32_16x16x32_bf16(as[1], fW4[1], Y4a, 0, 0, 0);
        Y5a = __builtin_amdgcn_mfma_f32_16x16x32_bf16(as[1], fW5[1], Y5a, 0, 0, 0);
        Y4b = __builtin_amdgcn_mfma_f32_16x16x32_bf16(as[3], fW4[3], Y4b, 0, 0, 0);
        Y5b = __builtin_amdgcn_mfma_f32_16x16x32_bf16(as[3], fW5[3], Y5b, 0, 0, 0);
        const f32x4 Y4 = Y4a + Y4b, Y5 = Y5a + Y5b;
        float knA[4], qqA[4];
#pragma unroll
        for (int i = 0; i < 4; ++i) {
            const float pk = sigm(Y4[i]) * tanh_(Y5[i]);
            const float kn = g[i] * kold[i] + (1.0f - g[i]) * pk;
            kold[i] = kn; knA[i] = kn;
            qqA[i] = kn - bf2f(inpN[i]);
        }
        {
            const u32 k01 = cvtpk(knA[0], knA[1]), k23 = cvtpk(knA[2], knA[3]);
            const u32 q01 = cvtpk(qqA[0], qqA[1]), q23 = cvtpk(qqA[2], qqA[3]);
            kbuf[quad * 4 + 0][col] = (u16)k01;
            kbuf[quad * 4 + 1][col] = (u16)(k01 >> 16);
            kbuf[quad * 4 + 2][col] = (u16)k23;
            kbuf[quad * 4 + 3][col] = (u16)(k23 >> 16);
            qqbuf[quad * 4 + 0][col] = (u16)q01;
            qqbuf[quad * 4 + 1][col] = (u16)(q01 >> 16);
            qqbuf[quad * 4 + 2][col] = (u16)q23;
            qqbuf[quad * 4 + 3][col] = (u16)(q23 >> 16);
        }
#pragma unroll
        for (int i = 0; i < 4; ++i) {
            z6c[i] = agv[i] + sw6[i] + qw6[i];
            ac[i] = an[i];
        }
        bar += 8; wgsync(&sctr, bar);
    }

#pragma unroll
    for (int i = 0; i < 4; ++i) {
        const int row = quad * 4 + i;
        const float v = sigm(kold[i]);
        const int off = (b0 + row) * EDIM + col;
        if (BF) ((u16*)outv)[off] = f2bf(v);
        else    ((float*)outv)[off] = v;
    }
}

// ---------------------------------------------------------------------------
extern "C" void kernel_launch(void* const* d_in, const int* in_sizes, int n_in,
                              void* d_out, int out_size, void* d_ws, size_t ws_size,
                              hipStream_t stream) {
    static const int exp_sizes[27] = {
        128000, 128000, 128000, 128000, 128000,
        128000, 128000, 128000, 128000,
        16384000,
        128128, 13056, 13056, 256, 128,
        65536, 128, 16384, 128, 16384, 128,
        32768, 128, 32768, 128, 65536, 128
    };
    bool sizes_ok = (n_in == 27) && (out_size == 32768);
    if (sizes_ok)
        for (int i = 0; i < 27; ++i)
            if (in_sizes[i] != exp_sizes[i]) { sizes_ok = false; break; }
    if (!sizes_ok) {
        dimkt_sentinel<<<dim3(128), dim3(256), 0, stream>>>((u16*)d_out, (u16)0xC080); // -4.0
        return;
    }
    const size_t WS_NEED = 724480;                       // f32 tables
    const size_t WS_FB   = WS_NEED + 32768000u;          // + INP16 (proven tier, R6)
    if (ws_size < WS_FB) {
        dimkt_sentinel<<<dim3(128), dim3(256), 0, stream>>>((u16*)d_out, (u16)0x4110); // 9.0
        return;
    }
    const size_t WS_PK   = WS_NEED + 65536000u;          // INPZ6T u32
    const size_t WS_FAST = WS_PK + 32768000u + 131072u;  // + qe16 + W1bf
    const int pk   = (ws_size >= WS_PK) ? 1 : 0;
    const int fast = (ws_size >= WS_FAST) ? 1 : 0;

    const int* c   = (const int*)d_in[1];
    const int* sd  = (const int*)d_in[2];
    const int* qd  = (const int*)d_in[3];
    const int* a   = (const int*)d_in[4];
    const void* q_emb = d_in[9];
    const void* c_tab = d_in[10];
    const void* sd_tab = d_in[11];
    const void* qd_tab = d_in[12];
    const void* a_tab = d_in[13];
    const void* knowledge = d_in[14];
    const void* W1 = d_in[15]; const void* b1 = d_in[16];
    const void* W2 = d_in[17]; const void* b2 = d_in[18];
    const void* W3 = d_in[19]; const void* b3 = d_in[20];
    const void* W4 = d_in[21]; const void* b4 = d_in[22];
    const void* W5 = d_in[23]; const void* b5 = d_in[24];
    const void* W6 = d_in[25]; const void* b6 = d_in[26];

    float* wsf = (float*)d_ws;
    float* cW1p = wsf;                 // 1001*128
    float* sdQ  = wsf + 128128;        // 102*256
    float* qdQ  = wsf + 154240;        // 102*256
    float* aW6p = wsf + 180352;        // 2*128 (+b6)
    float* c4t  = wsf + 180608;        // 2*128 (+b4)
    float* c5t  = wsf + 180864;        // 2*128 (+b5)
    u16* INP16  = (u16*)((char*)d_ws + WS_NEED);   // FB tier payload
    u32* INPZ6T = (u32*)((char*)d_ws + WS_NEED);   // PK tier payload (same slot)
    u16* qe16   = (u16*)((char*)d_ws + WS_PK);
    u16* W1b    = (u16*)((char*)d_ws + WS_PK + 32768000u);

    dimkt_tabs<<<dim3(1415), dim3(128), 0, stream>>>(
        q_emb, c_tab, sd_tab, qd_tab, a_tab, W1, W4, W5, W6, b4, b5, b6,
        cW1p, sdQ, qdQ, aW6p, c4t, c5t);

    if (fast) {
        dimkt_qe16<<<dim3(8000), dim3(256), 0, stream>>>((const float*)q_emb, qe16);
        dimkt_w1bf<<<dim3(256), dim3(256), 0, stream>>>(W1, q_emb, W1b);
    }

    dimkt_inp<<<dim3(500, 16), dim3(64), 0, stream>>>(
        q_emb, qe16, W1b, fast, W1, b1, c, sd, qd, a,
        cW1p, sdQ, qdQ, aW6p, INP16, INPZ6T, pk);

    if (pk) {
        dimkt_scan_pk<true><<<dim3(16), dim3(512), 0, stream>>>(
            q_emb, INPZ6T, a, W2, b2, W3, b3, W4, W5, W6, knowledge, c4t, c5t, d_out);
        dimkt_scan_pk<false><<<dim3(16), dim3(512), 0, stream>>>(
            q_emb, INPZ6T, a, W2, b2, W3, b3, W4, W5, W6, knowledge, c4t, c5t, d_out);
    } else {
        constexpr int DYN_BYTES = 2 * 102 * 130 * 2 + 2 * 132 * 4;   // 54,096 B
        hipFuncSetAttribute(reinterpret_cast<const void*>(&dimkt_scan_fb<true>),
                            hipFuncAttributeMaxDynamicSharedMemorySize, DYN_BYTES);
        hipFuncSetAttribute(reinterpret_cast<const void*>(&dimkt_scan_fb<false>),
                            hipFuncAttributeMaxDynamicSharedMemorySize, DYN_BYTES);
        dimkt_scan_fb<true><<<dim3(16), dim3(512), DYN_BYTES, stream>>>(
            q_emb, INP16, c, sd, qd, a, W2, b2, W3, b3, W4, W5, W6, knowledge,
            sdQ, qdQ, aW6p, c4t, c5t, d_out);
        dimkt_scan_fb<false><<<dim3(16), dim3(512), DYN_BYTES, stream>>>(
            q_emb, INP16, c, sd, qd, a, W2, b2, W3, b3, W4, W5, W6, knowledge,
            sdQ, qdQ, aW6p, c4t, c5t, d_out);
    }
}